// Round 7
// baseline (381.780 us; speedup 1.0000x reference)
//
#include <hip/hip_runtime.h>
#include <hip/hip_bf16.h>
#include <stdint.h>

#define GCN_N 50000
#define GCN_E 800000
#define GCN_D 256

typedef __attribute__((ext_vector_type(8))) short bf16x8;
typedef __attribute__((ext_vector_type(4))) float f32x4;
typedef unsigned short ushort_t;
typedef unsigned long long u64;

__device__ __forceinline__ float bf2f(ushort_t u) {
    return __uint_as_float(((unsigned)u) << 16);
}
__device__ __forceinline__ ushort_t f2bf(float f) {
    unsigned v = __float_as_uint(f);
    v += 0x7FFFu + ((v >> 16) & 1u);   // round-to-nearest-even
    return (ushort_t)(v >> 16);
}

// ---------------- preprocessing kernels ----------------

__global__ void init_kernel(u64* dc, int n) {
    int i = blockIdx.x * blockDim.x + threadIdx.x;
    if (i < n) dc[i] = 0ull;
}

// dc[d] packs: count in bits [40..], sum(w) as 2^-32 fixed point in bits [0..40)
// atomic return value's count field = this edge's rank among its dst's edges.
__global__ void edge_mlp_kernel(const float* __restrict__ attr,
                                const int* __restrict__ dst,
                                const float* __restrict__ mw1, const float* __restrict__ mb1,
                                const float* __restrict__ mw2, const float* __restrict__ mb2,
                                float* __restrict__ ew, u64* __restrict__ dc,
                                int* __restrict__ rank, int e_count) {
    int e = blockIdx.x * blockDim.x + threadIdx.x;
    if (e >= e_count) return;
    float a = attr[e];
    float s = mb2[0];
#pragma unroll
    for (int j = 0; j < 8; ++j) {
        float hj = fmaf(a, mw1[j], mb1[j]);
        hj = fmaxf(hj, 0.0f);
        s = fmaf(hj, mw2[j], s);
    }
    float w = 1.0f / (1.0f + expf(-s));
    ew[e] = w;
    u64 pack = (1ull << 40) + (u64)((double)w * 4294967296.0);
    u64 old = atomicAdd(&dc[dst[e]], pack);
    rank[e] = (int)(old >> 40);
}

__global__ void node_kernel(const u64* __restrict__ dc, float* __restrict__ dinv,
                            float* __restrict__ invdeg, int n) {
    int i = blockIdx.x * blockDim.x + threadIdx.x;
    if (i < n) {
        u64 v = dc[i];
        float wsum = (float)((double)(v & ((1ull << 40) - 1)) * (1.0 / 4294967296.0));
        float d = 1.0f + wsum;
        dinv[i] = rsqrtf(d);
        invdeg[i] = 1.0f / d;
    }
}

__global__ __launch_bounds__(1024) void scan1_kernel(const u64* __restrict__ dc,
                                                     int* __restrict__ part,
                                                     int* __restrict__ bsum, int n) {
    __shared__ int s[1024];
    int tid = threadIdx.x;
    int i = blockIdx.x * 1024 + tid;
    int v = (i < n) ? (int)(dc[i] >> 40) : 0;
    s[tid] = v;
    __syncthreads();
#pragma unroll
    for (int d = 1; d < 1024; d <<= 1) {
        int t = (tid >= d) ? s[tid - d] : 0;
        __syncthreads();
        s[tid] += t;
        __syncthreads();
    }
    if (i < n) part[i] = s[tid] - v;  // exclusive within block
    if (tid == 1023) bsum[blockIdx.x] = s[1023];
}

// wave64 shuffle scan over block sums (nb <= 64)
__global__ void scan2_kernel(int* bsum, int nb) {
    int t = threadIdx.x;
    int orig = (t < nb) ? bsum[t] : 0;
    int v = orig;
#pragma unroll
    for (int d = 1; d < 64; d <<= 1) {
        int u = __shfl_up(v, d, 64);
        if (t >= d) v += u;
    }
    if (t < nb) bsum[t] = v - orig;   // exclusive
}

__global__ void scan3_kernel(const int* __restrict__ part, const int* __restrict__ bsum,
                             int* __restrict__ offs, int n, int e_total) {
    int i = blockIdx.x * blockDim.x + threadIdx.x;
    if (i < n) offs[i] = part[i] + bsum[i >> 10];
    if (i == 0) offs[n] = e_total;
}

// no atomics: position = offs[dst] + rank captured in edge_mlp
__global__ void scatter_kernel(const int* __restrict__ src, const int* __restrict__ dst,
                               const float* __restrict__ ew, const float* __restrict__ dinv,
                               const int* __restrict__ offs, const int* __restrict__ rank,
                               int2* __restrict__ csr, int e_count) {
    int e = blockIdx.x * blockDim.x + threadIdx.x;
    if (e >= e_count) return;
    int sN = src[e], dN = dst[e];
    int pos = offs[dN] + rank[e];
    float w = dinv[sN] * ew[e] * dinv[dN];
    csr[pos] = make_int2(sN, __float_as_int(w));
}

// ---------------- W -> bf16 hi/lo split in MFMA-fragment-major layout ----------------
// wtf[((kt*16 + nt)*64 + lane)*8 + j] = bf16(W[kt*32 + (lane>>4)*8 + j][nt*16 + (lane&15)])

__global__ __launch_bounds__(256) void wconvert_kernel(const float* __restrict__ W,
                                                       ushort_t* __restrict__ wtf_hi,
                                                       ushort_t* __restrict__ wtf_lo) {
    __shared__ ushort_t lds_hi[32][256];
    __shared__ ushort_t lds_lo[32][256];
    const int kt = blockIdx.x;
    const int tid = threadIdx.x;
    for (int c = 0; c < 32; ++c) {
        float f = W[(kt * 32 + c) * GCN_D + tid];
        unsigned u = __float_as_uint(f);
        ushort_t hi = (ushort_t)(u >> 16);               // truncation: exact residual
        float r = f - __uint_as_float(u & 0xFFFF0000u);
        lds_hi[c][tid] = hi;
        lds_lo[c][tid] = f2bf(r);
    }
    __syncthreads();
#pragma unroll
    for (int q = 0; q < 4; ++q) {
        int slot = q * 256 + tid;          // 0..1023 = nt*64 + lane
        int lane = slot & 63, nt = slot >> 6;
        int n = nt * 16 + (lane & 15);
        int kl = (lane >> 4) * 8;
        ushort_t h8[8], l8[8];
#pragma unroll
        for (int j = 0; j < 8; ++j) { h8[j] = lds_hi[kl + j][n]; l8[j] = lds_lo[kl + j][n]; }
        size_t o = ((size_t)(kt * 16 + nt) * 64 + lane) * 8;
#pragma unroll
        for (int j = 0; j < 8; ++j) { wtf_hi[o + j] = h8[j]; wtf_lo[o + j] = l8[j]; }
    }
}

// ---------------- MFMA GEMM (layer 1): fp32 x, split-precision ----------------
// Block = 32 rows x 256 cols, 4 waves; wave = 16 rows x 128 cols (8 Ntiles).
// Per kt: A-load first, then ALL 16 B-fragment loads batched into registers
// (17 vmem ops in flight), split overlaps B latency, then 24 MFMAs.

__device__ __forceinline__ void split_f32x8(float4 f0, float4 f1, bf16x8& hi, bf16x8& lo) {
    float f[8] = {f0.x, f0.y, f0.z, f0.w, f1.x, f1.y, f1.z, f1.w};
#pragma unroll
    for (int i = 0; i < 8; ++i) {
        unsigned u = __float_as_uint(f[i]);
        hi[i] = (short)(u >> 16);
        float r = f[i] - __uint_as_float(u & 0xFFFF0000u);
        lo[i] = (short)f2bf(r);
    }
}

__global__ __launch_bounds__(256) void mfma_gemm_f32_kernel(
        const float* __restrict__ x,          // [n_rows][256] fp32
        const ushort_t* __restrict__ wtf_hi,  // fragment-major bf16 bits
        const ushort_t* __restrict__ wtf_lo,
        const float* __restrict__ bias,
        ushort_t* __restrict__ out_h,         // [n_rows][256] bf16
        int n_rows) {
    __shared__ ushort_t csmem[4 * 16 * 132];
    const int lane = threadIdx.x & 63;
    const int wv   = threadIdx.x >> 6;
    const int r16  = lane & 15;
    const int kg   = lane >> 4;
    const int row0 = blockIdx.x * 32 + (wv >> 1) * 16;
    const int nt0  = (wv & 1) * 8;

    f32x4 acc[8];
#pragma unroll
    for (int nt = 0; nt < 8; ++nt) acc[nt] = (f32x4){0.f, 0.f, 0.f, 0.f};

    const int arow = row0 + r16;
    const float* ap = (arow < n_rows) ? &x[(size_t)arow * GCN_D + kg * 8] : nullptr;

#pragma unroll 1
    for (int kt = 0; kt < 8; ++kt) {
        // issue A load first
        float4 f0 = make_float4(0.f, 0.f, 0.f, 0.f), f1 = f0;
        if (ap) {
            f0 = *(const float4*)(ap + kt * 32);
            f1 = *(const float4*)(ap + kt * 32 + 4);
        }
        // batch ALL B loads (independent, stay in flight during split)
        const bf16x8* bhp = (const bf16x8*)wtf_hi + ((size_t)kt * 16 + nt0) * 64 + lane;
        const bf16x8* blp = (const bf16x8*)wtf_lo + ((size_t)kt * 16 + nt0) * 64 + lane;
        bf16x8 bh[8], bl[8];
#pragma unroll
        for (int nt = 0; nt < 8; ++nt) bh[nt] = bhp[nt * 64];
#pragma unroll
        for (int nt = 0; nt < 8; ++nt) bl[nt] = blp[nt * 64];
        // split (VALU) overlaps B-load latency
        bf16x8 a_hi, a_lo;
        split_f32x8(f0, f1, a_hi, a_lo);
#pragma unroll
        for (int nt = 0; nt < 8; ++nt) {
            acc[nt] = __builtin_amdgcn_mfma_f32_16x16x32_bf16(a_hi, bh[nt], acc[nt], 0, 0, 0);
            acc[nt] = __builtin_amdgcn_mfma_f32_16x16x32_bf16(a_lo, bh[nt], acc[nt], 0, 0, 0);
            acc[nt] = __builtin_amdgcn_mfma_f32_16x16x32_bf16(a_hi, bl[nt], acc[nt], 0, 0, 0);
        }
    }

    // C layout: col = lane&15, row = (lane>>4)*4 + reg. Wave-private LDS tile.
    ushort_t* my = csmem + wv * (16 * 132);
#pragma unroll
    for (int nt = 0; nt < 8; ++nt) {
        float bv = bias[(nt0 + nt) * 16 + r16];
#pragma unroll
        for (int r = 0; r < 4; ++r)
            my[(kg * 4 + r) * 132 + nt * 16 + r16] = f2bf(acc[nt][r] + bv);
    }
#pragma unroll 4
    for (int r = 0; r < 16; ++r) {
        int row = row0 + r;
        if (row < n_rows) {
            unsigned v = *(unsigned*)&my[r * 132 + lane * 2];
            *(unsigned*)&out_h[(size_t)row * GCN_D + nt0 * 16 + lane * 2] = v;
        }
    }
}

// ---------------- MFMA GEMM (layers 2,3): bf16 A, W_hi only ----------------

__global__ __launch_bounds__(256) void mfma_gemm_bf16_kernel(
        const ushort_t* __restrict__ a_in,    // [n_rows][256] bf16
        const ushort_t* __restrict__ wtf_hi,
        const float* __restrict__ bias,
        ushort_t* __restrict__ out_h,         // [n_rows][256] bf16
        int n_rows) {
    __shared__ ushort_t csmem[4 * 16 * 132];
    const int lane = threadIdx.x & 63;
    const int wv   = threadIdx.x >> 6;
    const int r16  = lane & 15;
    const int kg   = lane >> 4;
    const int row0 = blockIdx.x * 32 + (wv >> 1) * 16;
    const int nt0  = (wv & 1) * 8;

    f32x4 acc[8];
#pragma unroll
    for (int nt = 0; nt < 8; ++nt) acc[nt] = (f32x4){0.f, 0.f, 0.f, 0.f};

    const int arow = row0 + r16;
    const ushort_t* ap = (arow < n_rows) ? &a_in[(size_t)arow * GCN_D + kg * 8] : nullptr;

#pragma unroll 2
    for (int kt = 0; kt < 8; ++kt) {
        bf16x8 a = (bf16x8){0, 0, 0, 0, 0, 0, 0, 0};
        if (ap) a = *(const bf16x8*)(ap + kt * 32);
        const bf16x8* bhp = (const bf16x8*)wtf_hi + ((size_t)kt * 16 + nt0) * 64 + lane;
        bf16x8 bh[8];
#pragma unroll
        for (int nt = 0; nt < 8; ++nt) bh[nt] = bhp[nt * 64];
#pragma unroll
        for (int nt = 0; nt < 8; ++nt)
            acc[nt] = __builtin_amdgcn_mfma_f32_16x16x32_bf16(a, bh[nt], acc[nt], 0, 0, 0);
    }

    ushort_t* my = csmem + wv * (16 * 132);
#pragma unroll
    for (int nt = 0; nt < 8; ++nt) {
        float bv = bias[(nt0 + nt) * 16 + r16];
#pragma unroll
        for (int r = 0; r < 4; ++r)
            my[(kg * 4 + r) * 132 + nt * 16 + r16] = f2bf(acc[nt][r] + bv);
    }
#pragma unroll 4
    for (int r = 0; r < 16; ++r) {
        int row = row0 + r;
        if (row < n_rows) {
            unsigned v = *(unsigned*)&my[r * 132 + lane * 2];
            *(unsigned*)&out_h[(size_t)row * GCN_D + nt0 * 16 + lane * 2] = v;
        }
    }
}

// ---------------- SpMM: agg = A_norm*h + diag(1/deg)*h ----------------
// one wave per node; bf16 gathers (8B/lane), CSR packed int2, 16 gathers in flight.
// OUT_BF16: write bf16 + relu (layers 1,2). else fp32, no relu (layer 3).

template <int OUT_BF16>
__global__ __launch_bounds__(256) void spmm_kernel(const ushort_t* __restrict__ h,
                                                   const int* __restrict__ offs,
                                                   const int2* __restrict__ csr,
                                                   const float* __restrict__ invdeg,
                                                   void* __restrict__ outp, int n) {
    int wid = (blockIdx.x * blockDim.x + threadIdx.x) >> 6;
    int lane = threadIdx.x & 63;
    if (wid >= n) return;
    const ushort4* h4 = (const ushort4*)h;
    ushort4 sv = h4[(size_t)wid * 64 + lane];
    float sw = invdeg[wid];
    float4 acc;
    acc.x = bf2f(sv.x) * sw; acc.y = bf2f(sv.y) * sw;
    acc.z = bf2f(sv.z) * sw; acc.w = bf2f(sv.w) * sw;
    int e0 = offs[wid], e1 = offs[wid + 1];
    int k = e0;
    for (; k + 16 <= e1; k += 16) {
        int2 ee[16]; ushort4 vv[16];
#pragma unroll
        for (int u = 0; u < 16; ++u) ee[u] = csr[k + u];
#pragma unroll
        for (int u = 0; u < 16; ++u) vv[u] = h4[(size_t)ee[u].x * 64 + lane];
#pragma unroll
        for (int u = 0; u < 16; ++u) {
            float w = __int_as_float(ee[u].y);
            acc.x = fmaf(w, bf2f(vv[u].x), acc.x);
            acc.y = fmaf(w, bf2f(vv[u].y), acc.y);
            acc.z = fmaf(w, bf2f(vv[u].z), acc.z);
            acc.w = fmaf(w, bf2f(vv[u].w), acc.w);
        }
    }
    if (k + 8 <= e1) {
        int2 ee[8]; ushort4 vv[8];
#pragma unroll
        for (int u = 0; u < 8; ++u) ee[u] = csr[k + u];
#pragma unroll
        for (int u = 0; u < 8; ++u) vv[u] = h4[(size_t)ee[u].x * 64 + lane];
#pragma unroll
        for (int u = 0; u < 8; ++u) {
            float w = __int_as_float(ee[u].y);
            acc.x = fmaf(w, bf2f(vv[u].x), acc.x);
            acc.y = fmaf(w, bf2f(vv[u].y), acc.y);
            acc.z = fmaf(w, bf2f(vv[u].z), acc.z);
            acc.w = fmaf(w, bf2f(vv[u].w), acc.w);
        }
        k += 8;
    }
    for (; k < e1; ++k) {
        int2 e = csr[k];
        float w = __int_as_float(e.y);
        ushort4 hv = h4[(size_t)e.x * 64 + lane];
        acc.x = fmaf(w, bf2f(hv.x), acc.x);
        acc.y = fmaf(w, bf2f(hv.y), acc.y);
        acc.z = fmaf(w, bf2f(hv.z), acc.z);
        acc.w = fmaf(w, bf2f(hv.w), acc.w);
    }
    if (OUT_BF16) {
        ushort4 o;
        o.x = f2bf(fmaxf(acc.x, 0.f));
        o.y = f2bf(fmaxf(acc.y, 0.f));
        o.z = f2bf(fmaxf(acc.z, 0.f));
        o.w = f2bf(fmaxf(acc.w, 0.f));
        ((ushort4*)outp)[(size_t)wid * 64 + lane] = o;
    } else {
        ((float4*)outp)[(size_t)wid * 64 + lane] = acc;
    }
}

// ---------------- launch ----------------

extern "C" void kernel_launch(void* const* d_in, const int* in_sizes, int n_in,
                              void* d_out, int out_size, void* d_ws, size_t ws_size,
                              hipStream_t stream) {
    const float* x    = (const float*)d_in[0];
    const int*   ei   = (const int*)d_in[1];
    const float* attr = (const float*)d_in[2];
    const float* W1 = (const float*)d_in[3];  const float* b1 = (const float*)d_in[4];
    const float* W2 = (const float*)d_in[5];  const float* b2 = (const float*)d_in[6];
    const float* W3 = (const float*)d_in[7];  const float* b3 = (const float*)d_in[8];
    const float* mw1 = (const float*)d_in[9]; const float* mb1 = (const float*)d_in[10];
    const float* mw2 = (const float*)d_in[11];const float* mb2 = (const float*)d_in[12];
    float* out = (float*)d_out;

    const int N = GCN_N, E = GCN_E;
    const int* srcI = ei;
    const int* dstI = ei + E;

    char* ws = (char*)d_ws;
    float* ew     = (float*)ws;                      ws += (size_t)E * 4;
    int*   rank   = (int*)ws;                        ws += (size_t)E * 4;
    u64*   dc     = (u64*)(((uintptr_t)ws + 255) & ~(uintptr_t)255); ws = (char*)(dc + N);
    float* dinv   = (float*)ws;                      ws += (size_t)N * 4;
    float* invdeg = (float*)ws;                      ws += (size_t)N * 4;
    int*   offs   = (int*)ws;                        ws += (size_t)(N + 1) * 4;
    int*   bsum   = (int*)ws;                        ws += 64 * 4;
    int*   part   = (int*)ws;                        ws += (size_t)N * 4;
    int2*  csr    = (int2*)(((uintptr_t)ws + 255) & ~(uintptr_t)255); ws = (char*)(csr + E);
    ushort_t* h   = (ushort_t*)(((uintptr_t)ws + 255) & ~(uintptr_t)255);  // N*256 bf16
    ws = (char*)(h + (size_t)N * GCN_D);
    ushort_t* act = (ushort_t*)(((uintptr_t)ws + 255) & ~(uintptr_t)255);  // N*256 bf16
    ws = (char*)(act + (size_t)N * GCN_D);
    ushort_t* wtf = (ushort_t*)(((uintptr_t)ws + 255) & ~(uintptr_t)255);
    ushort_t* wtf_hi1 = wtf;            // 65536 each
    ushort_t* wtf_lo1 = wtf + 65536;
    ushort_t* wtf_hi2 = wtf + 2 * 65536;
    ushort_t* wtf_lo2 = wtf + 3 * 65536;
    ushort_t* wtf_hi3 = wtf + 4 * 65536;
    ushort_t* wtf_lo3 = wtf + 5 * 65536;

    init_kernel<<<(N + 255) / 256, 256, 0, stream>>>(dc, N);
    edge_mlp_kernel<<<(E + 255) / 256, 256, 0, stream>>>(attr, dstI, mw1, mb1, mw2, mb2,
                                                         ew, dc, rank, E);
    node_kernel<<<(N + 255) / 256, 256, 0, stream>>>(dc, dinv, invdeg, N);
    int nb = (N + 1023) / 1024;
    scan1_kernel<<<nb, 1024, 0, stream>>>(dc, part, bsum, N);
    scan2_kernel<<<1, 64, 0, stream>>>(bsum, nb);
    scan3_kernel<<<(N + 255) / 256, 256, 0, stream>>>(part, bsum, offs, N, E);
    scatter_kernel<<<(E + 255) / 256, 256, 0, stream>>>(srcI, dstI, ew, dinv, offs, rank,
                                                        csr, E);
    wconvert_kernel<<<8, 256, 0, stream>>>(W1, wtf_hi1, wtf_lo1);
    wconvert_kernel<<<8, 256, 0, stream>>>(W2, wtf_hi2, wtf_lo2);
    wconvert_kernel<<<8, 256, 0, stream>>>(W3, wtf_hi3, wtf_lo3);

    const int gemm_grid = (N + 31) / 32;
    const int spmm_grid = (N * 64 + 255) / 256;

    // layer 1: x fp32 -> h ; spmm -> act (bf16, relu)
    mfma_gemm_f32_kernel<<<gemm_grid, 256, 0, stream>>>(x, wtf_hi1, wtf_lo1, b1, h, N);
    spmm_kernel<1><<<spmm_grid, 256, 0, stream>>>(h, offs, csr, invdeg, act, N);
    // layer 2: act bf16 -> h ; spmm -> act
    mfma_gemm_bf16_kernel<<<gemm_grid, 256, 0, stream>>>(act, wtf_hi2, b2, h, N);
    spmm_kernel<1><<<spmm_grid, 256, 0, stream>>>(h, offs, csr, invdeg, act, N);
    // layer 3: act bf16 -> h ; spmm -> d_out (fp32, no relu)
    mfma_gemm_bf16_kernel<<<gemm_grid, 256, 0, stream>>>(act, wtf_hi3, b3, h, N);
    spmm_kernel<0><<<spmm_grid, 256, 0, stream>>>(h, offs, csr, invdeg, out, N);
}

// Round 8
// 356.323 us; speedup vs baseline: 1.0714x; 1.0714x over previous
//
#include <hip/hip_runtime.h>
#include <hip/hip_bf16.h>
#include <stdint.h>

#define GCN_N 50000
#define GCN_E 800000
#define GCN_D 256

typedef __attribute__((ext_vector_type(8))) short bf16x8;
typedef __attribute__((ext_vector_type(4))) float f32x4;
typedef unsigned short ushort_t;
typedef unsigned long long u64;

__device__ __forceinline__ float bf2f(ushort_t u) {
    return __uint_as_float(((unsigned)u) << 16);
}
__device__ __forceinline__ ushort_t f2bf(float f) {
    unsigned v = __float_as_uint(f);
    v += 0x7FFFu + ((v >> 16) & 1u);   // round-to-nearest-even
    return (ushort_t)(v >> 16);
}

// ---------------- preprocessing kernels ----------------

__global__ void init_kernel(u64* dc, int n) {
    int i = blockIdx.x * blockDim.x + threadIdx.x;
    if (i < n) dc[i] = 0ull;
}

// dc[d] packs: count in bits [40..], sum(w) as 2^-32 fixed point in bits [0..40)
// atomic return value's count field = this edge's rank among its dst's edges.
__global__ void edge_mlp_kernel(const float* __restrict__ attr,
                                const int* __restrict__ dst,
                                const float* __restrict__ mw1, const float* __restrict__ mb1,
                                const float* __restrict__ mw2, const float* __restrict__ mb2,
                                float* __restrict__ ew, u64* __restrict__ dc,
                                int* __restrict__ rank, int e_count) {
    int e = blockIdx.x * blockDim.x + threadIdx.x;
    if (e >= e_count) return;
    float a = attr[e];
    float s = mb2[0];
#pragma unroll
    for (int j = 0; j < 8; ++j) {
        float hj = fmaf(a, mw1[j], mb1[j]);
        hj = fmaxf(hj, 0.0f);
        s = fmaf(hj, mw2[j], s);
    }
    float w = 1.0f / (1.0f + expf(-s));
    ew[e] = w;
    u64 pack = (1ull << 40) + (u64)((double)w * 4294967296.0);
    u64 old = atomicAdd(&dc[dst[e]], pack);
    rank[e] = (int)(old >> 40);
}

__global__ void node_kernel(const u64* __restrict__ dc, float* __restrict__ dinv,
                            float* __restrict__ invdeg, int n) {
    int i = blockIdx.x * blockDim.x + threadIdx.x;
    if (i < n) {
        u64 v = dc[i];
        float wsum = (float)((double)(v & ((1ull << 40) - 1)) * (1.0 / 4294967296.0));
        float d = 1.0f + wsum;
        dinv[i] = rsqrtf(d);
        invdeg[i] = 1.0f / d;
    }
}

__global__ __launch_bounds__(1024) void scan1_kernel(const u64* __restrict__ dc,
                                                     int* __restrict__ part,
                                                     int* __restrict__ bsum, int n) {
    __shared__ int s[1024];
    int tid = threadIdx.x;
    int i = blockIdx.x * 1024 + tid;
    int v = (i < n) ? (int)(dc[i] >> 40) : 0;
    s[tid] = v;
    __syncthreads();
#pragma unroll
    for (int d = 1; d < 1024; d <<= 1) {
        int t = (tid >= d) ? s[tid - d] : 0;
        __syncthreads();
        s[tid] += t;
        __syncthreads();
    }
    if (i < n) part[i] = s[tid] - v;  // exclusive within block
    if (tid == 1023) bsum[blockIdx.x] = s[1023];
}

// wave64 shuffle scan over block sums (nb <= 64)
__global__ void scan2_kernel(int* bsum, int nb) {
    int t = threadIdx.x;
    int orig = (t < nb) ? bsum[t] : 0;
    int v = orig;
#pragma unroll
    for (int d = 1; d < 64; d <<= 1) {
        int u = __shfl_up(v, d, 64);
        if (t >= d) v += u;
    }
    if (t < nb) bsum[t] = v - orig;   // exclusive
}

__global__ void scan3_kernel(const int* __restrict__ part, const int* __restrict__ bsum,
                             int* __restrict__ offs, int n, int e_total) {
    int i = blockIdx.x * blockDim.x + threadIdx.x;
    if (i < n) offs[i] = part[i] + bsum[i >> 10];
    if (i == 0) offs[n] = e_total;
}

// no atomics: position = offs[dst] + rank captured in edge_mlp
__global__ void scatter_kernel(const int* __restrict__ src, const int* __restrict__ dst,
                               const float* __restrict__ ew, const float* __restrict__ dinv,
                               const int* __restrict__ offs, const int* __restrict__ rank,
                               int2* __restrict__ csr, int e_count) {
    int e = blockIdx.x * blockDim.x + threadIdx.x;
    if (e >= e_count) return;
    int sN = src[e], dN = dst[e];
    int pos = offs[dN] + rank[e];
    float w = dinv[sN] * ew[e] * dinv[dN];
    csr[pos] = make_int2(sN, __float_as_int(w));
}

// ---------------- W -> bf16 hi/lo split in MFMA-fragment-major layout ----------------
// wtf[((kt*16 + nt)*64 + lane)*8 + j] = bf16(W[kt*32 + (lane>>4)*8 + j][nt*16 + (lane&15)])

__global__ __launch_bounds__(256) void wconvert_kernel(const float* __restrict__ W,
                                                       ushort_t* __restrict__ wtf_hi,
                                                       ushort_t* __restrict__ wtf_lo) {
    __shared__ ushort_t lds_hi[32][256];
    __shared__ ushort_t lds_lo[32][256];
    const int kt = blockIdx.x;
    const int tid = threadIdx.x;
    for (int c = 0; c < 32; ++c) {
        float f = W[(kt * 32 + c) * GCN_D + tid];
        unsigned u = __float_as_uint(f);
        ushort_t hi = (ushort_t)(u >> 16);               // truncation: exact residual
        float r = f - __uint_as_float(u & 0xFFFF0000u);
        lds_hi[c][tid] = hi;
        lds_lo[c][tid] = f2bf(r);
    }
    __syncthreads();
#pragma unroll
    for (int q = 0; q < 4; ++q) {
        int slot = q * 256 + tid;          // 0..1023 = nt*64 + lane
        int lane = slot & 63, nt = slot >> 6;
        int n = nt * 16 + (lane & 15);
        int kl = (lane >> 4) * 8;
        ushort_t h8[8], l8[8];
#pragma unroll
        for (int j = 0; j < 8; ++j) { h8[j] = lds_hi[kl + j][n]; l8[j] = lds_lo[kl + j][n]; }
        size_t o = ((size_t)(kt * 16 + nt) * 64 + lane) * 8;
#pragma unroll
        for (int j = 0; j < 8; ++j) { wtf_hi[o + j] = h8[j]; wtf_lo[o + j] = l8[j]; }
    }
}

// ---------------- MFMA GEMM (layer 1): fp32 x, split-precision, LDS-staged B ----------
// Block = 64 rows x 256 cols, 4 waves; wave = 16 rows x 256 cols (16 Ntiles, acc 64 VGPR).
// Per kt: stage 32KB of W frags (hi+lo) into LDS once per block (coalesced b128),
// barrier, ds_read_b128 fragments (stride-1: conflict-free), 48 MFMA, barrier.
// B L2 traffic: once per block (256KB) instead of once per wave -> 200MB total.

__device__ __forceinline__ void split_f32x8(float4 f0, float4 f1, bf16x8& hi, bf16x8& lo) {
    float f[8] = {f0.x, f0.y, f0.z, f0.w, f1.x, f1.y, f1.z, f1.w};
#pragma unroll
    for (int i = 0; i < 8; ++i) {
        unsigned u = __float_as_uint(f[i]);
        hi[i] = (short)(u >> 16);
        float r = f[i] - __uint_as_float(u & 0xFFFF0000u);
        lo[i] = (short)f2bf(r);
    }
}

__global__ __launch_bounds__(256) void mfma_gemm_f32_kernel(
        const float* __restrict__ x,          // [n_rows][256] fp32
        const ushort_t* __restrict__ wtf_hi,  // fragment-major bf16 bits
        const ushort_t* __restrict__ wtf_lo,
        const float* __restrict__ bias,
        ushort_t* __restrict__ out_h,         // [n_rows][256] bf16
        int n_rows) {
    __shared__ ushort_t smem[4 * 16 * 264];   // 33792B; stage area = first 32KB
    const int tid  = threadIdx.x;
    const int lane = tid & 63;
    const int wv   = tid >> 6;
    const int r16  = lane & 15;
    const int kg   = lane >> 4;
    const int row0 = blockIdx.x * 64 + wv * 16;

    f32x4 acc[16];
#pragma unroll
    for (int nt = 0; nt < 16; ++nt) acc[nt] = (f32x4){0.f, 0.f, 0.f, 0.f};

    const int arow = row0 + r16;
    const float* ap = (arow < n_rows) ? &x[(size_t)arow * GCN_D + kg * 8] : nullptr;
    bf16x8* sH = (bf16x8*)smem;        // 1024 fragments (16KB)
    bf16x8* sL = ((bf16x8*)smem) + 1024;

#pragma unroll 1
    for (int kt = 0; kt < 8; ++kt) {
        // A-load (independent of LDS)
        float4 f0 = make_float4(0.f, 0.f, 0.f, 0.f), f1 = f0;
        if (ap) {
            f0 = *(const float4*)(ap + kt * 32);
            f1 = *(const float4*)(ap + kt * 32 + 4);
        }
        // stage B for this kt: 256 threads x 4 chunks x 16B, coalesced
        const bf16x8* gh = (const bf16x8*)wtf_hi + (size_t)kt * 1024;
        const bf16x8* gl = (const bf16x8*)wtf_lo + (size_t)kt * 1024;
        bf16x8 t0 = gh[tid], t1 = gh[256 + tid], t2 = gh[512 + tid], t3 = gh[768 + tid];
        bf16x8 u0 = gl[tid], u1 = gl[256 + tid], u2 = gl[512 + tid], u3 = gl[768 + tid];
        sH[tid] = t0; sH[256 + tid] = t1; sH[512 + tid] = t2; sH[768 + tid] = t3;
        sL[tid] = u0; sL[256 + tid] = u1; sL[512 + tid] = u2; sL[768 + tid] = u3;
        bf16x8 a_hi, a_lo;
        split_f32x8(f0, f1, a_hi, a_lo);
        __syncthreads();
#pragma unroll
        for (int nt = 0; nt < 16; ++nt) {
            bf16x8 bh = sH[nt * 64 + lane];
            bf16x8 bl = sL[nt * 64 + lane];
            acc[nt] = __builtin_amdgcn_mfma_f32_16x16x32_bf16(a_hi, bh, acc[nt], 0, 0, 0);
            acc[nt] = __builtin_amdgcn_mfma_f32_16x16x32_bf16(a_lo, bh, acc[nt], 0, 0, 0);
            acc[nt] = __builtin_amdgcn_mfma_f32_16x16x32_bf16(a_hi, bl, acc[nt], 0, 0, 0);
        }
        __syncthreads();
    }

    // epilogue: reuse smem (all waves are past the final barrier; tiles wave-private)
    // C layout: col = lane&15, row = (lane>>4)*4 + reg
    ushort_t* my = smem + wv * (16 * 264);
#pragma unroll
    for (int nt = 0; nt < 16; ++nt) {
        float bv = bias[nt * 16 + r16];
#pragma unroll
        for (int r = 0; r < 4; ++r)
            my[(kg * 4 + r) * 264 + nt * 16 + r16] = f2bf(acc[nt][r] + bv);
    }
#pragma unroll 4
    for (int r = 0; r < 16; ++r) {
        int row = row0 + r;
        if (row < n_rows) {
            ushort4 v = *(ushort4*)&my[r * 264 + lane * 4];
            *(ushort4*)&out_h[(size_t)row * GCN_D + lane * 4] = v;
        }
    }
}

// ---------------- MFMA GEMM (layers 2,3): bf16 A, W_hi only, LDS-staged B ------------

__global__ __launch_bounds__(256) void mfma_gemm_bf16_kernel(
        const ushort_t* __restrict__ a_in,    // [n_rows][256] bf16
        const ushort_t* __restrict__ wtf_hi,
        const float* __restrict__ bias,
        ushort_t* __restrict__ out_h,         // [n_rows][256] bf16
        int n_rows) {
    __shared__ ushort_t smem[4 * 16 * 264];
    const int tid  = threadIdx.x;
    const int lane = tid & 63;
    const int wv   = tid >> 6;
    const int r16  = lane & 15;
    const int kg   = lane >> 4;
    const int row0 = blockIdx.x * 64 + wv * 16;

    f32x4 acc[16];
#pragma unroll
    for (int nt = 0; nt < 16; ++nt) acc[nt] = (f32x4){0.f, 0.f, 0.f, 0.f};

    const int arow = row0 + r16;
    const ushort_t* ap = (arow < n_rows) ? &a_in[(size_t)arow * GCN_D + kg * 8] : nullptr;
    bf16x8* sH = (bf16x8*)smem;

#pragma unroll 1
    for (int kt = 0; kt < 8; ++kt) {
        bf16x8 a = (bf16x8){0, 0, 0, 0, 0, 0, 0, 0};
        if (ap) a = *(const bf16x8*)(ap + kt * 32);
        const bf16x8* gh = (const bf16x8*)wtf_hi + (size_t)kt * 1024;
        bf16x8 t0 = gh[tid], t1 = gh[256 + tid], t2 = gh[512 + tid], t3 = gh[768 + tid];
        sH[tid] = t0; sH[256 + tid] = t1; sH[512 + tid] = t2; sH[768 + tid] = t3;
        __syncthreads();
#pragma unroll
        for (int nt = 0; nt < 16; ++nt) {
            bf16x8 bh = sH[nt * 64 + lane];
            acc[nt] = __builtin_amdgcn_mfma_f32_16x16x32_bf16(a, bh, acc[nt], 0, 0, 0);
        }
        __syncthreads();
    }

    ushort_t* my = smem + wv * (16 * 264);
#pragma unroll
    for (int nt = 0; nt < 16; ++nt) {
        float bv = bias[nt * 16 + r16];
#pragma unroll
        for (int r = 0; r < 4; ++r)
            my[(kg * 4 + r) * 264 + nt * 16 + r16] = f2bf(acc[nt][r] + bv);
    }
#pragma unroll 4
    for (int r = 0; r < 16; ++r) {
        int row = row0 + r;
        if (row < n_rows) {
            ushort4 v = *(ushort4*)&my[r * 264 + lane * 4];
            *(ushort4*)&out_h[(size_t)row * GCN_D + lane * 4] = v;
        }
    }
}

// ---------------- SpMM: agg = A_norm*h + diag(1/deg)*h ----------------
// one wave per node; bf16 gathers (8B/lane), CSR packed int2, 16 gathers in flight.
// OUT_BF16: write bf16 + relu (layers 1,2). else fp32, no relu (layer 3).

template <int OUT_BF16>
__global__ __launch_bounds__(256) void spmm_kernel(const ushort_t* __restrict__ h,
                                                   const int* __restrict__ offs,
                                                   const int2* __restrict__ csr,
                                                   const float* __restrict__ invdeg,
                                                   void* __restrict__ outp, int n) {
    int wid = (blockIdx.x * blockDim.x + threadIdx.x) >> 6;
    int lane = threadIdx.x & 63;
    if (wid >= n) return;
    const ushort4* h4 = (const ushort4*)h;
    ushort4 sv = h4[(size_t)wid * 64 + lane];
    float sw = invdeg[wid];
    float4 acc;
    acc.x = bf2f(sv.x) * sw; acc.y = bf2f(sv.y) * sw;
    acc.z = bf2f(sv.z) * sw; acc.w = bf2f(sv.w) * sw;
    int e0 = offs[wid], e1 = offs[wid + 1];
    int k = e0;
    for (; k + 16 <= e1; k += 16) {
        int2 ee[16]; ushort4 vv[16];
#pragma unroll
        for (int u = 0; u < 16; ++u) ee[u] = csr[k + u];
#pragma unroll
        for (int u = 0; u < 16; ++u) vv[u] = h4[(size_t)ee[u].x * 64 + lane];
#pragma unroll
        for (int u = 0; u < 16; ++u) {
            float w = __int_as_float(ee[u].y);
            acc.x = fmaf(w, bf2f(vv[u].x), acc.x);
            acc.y = fmaf(w, bf2f(vv[u].y), acc.y);
            acc.z = fmaf(w, bf2f(vv[u].z), acc.z);
            acc.w = fmaf(w, bf2f(vv[u].w), acc.w);
        }
    }
    if (k + 8 <= e1) {
        int2 ee[8]; ushort4 vv[8];
#pragma unroll
        for (int u = 0; u < 8; ++u) ee[u] = csr[k + u];
#pragma unroll
        for (int u = 0; u < 8; ++u) vv[u] = h4[(size_t)ee[u].x * 64 + lane];
#pragma unroll
        for (int u = 0; u < 8; ++u) {
            float w = __int_as_float(ee[u].y);
            acc.x = fmaf(w, bf2f(vv[u].x), acc.x);
            acc.y = fmaf(w, bf2f(vv[u].y), acc.y);
            acc.z = fmaf(w, bf2f(vv[u].z), acc.z);
            acc.w = fmaf(w, bf2f(vv[u].w), acc.w);
        }
        k += 8;
    }
    for (; k < e1; ++k) {
        int2 e = csr[k];
        float w = __int_as_float(e.y);
        ushort4 hv = h4[(size_t)e.x * 64 + lane];
        acc.x = fmaf(w, bf2f(hv.x), acc.x);
        acc.y = fmaf(w, bf2f(hv.y), acc.y);
        acc.z = fmaf(w, bf2f(hv.z), acc.z);
        acc.w = fmaf(w, bf2f(hv.w), acc.w);
    }
    if (OUT_BF16) {
        ushort4 o;
        o.x = f2bf(fmaxf(acc.x, 0.f));
        o.y = f2bf(fmaxf(acc.y, 0.f));
        o.z = f2bf(fmaxf(acc.z, 0.f));
        o.w = f2bf(fmaxf(acc.w, 0.f));
        ((ushort4*)outp)[(size_t)wid * 64 + lane] = o;
    } else {
        ((float4*)outp)[(size_t)wid * 64 + lane] = acc;
    }
}

// ---------------- launch ----------------

extern "C" void kernel_launch(void* const* d_in, const int* in_sizes, int n_in,
                              void* d_out, int out_size, void* d_ws, size_t ws_size,
                              hipStream_t stream) {
    const float* x    = (const float*)d_in[0];
    const int*   ei   = (const int*)d_in[1];
    const float* attr = (const float*)d_in[2];
    const float* W1 = (const float*)d_in[3];  const float* b1 = (const float*)d_in[4];
    const float* W2 = (const float*)d_in[5];  const float* b2 = (const float*)d_in[6];
    const float* W3 = (const float*)d_in[7];  const float* b3 = (const float*)d_in[8];
    const float* mw1 = (const float*)d_in[9]; const float* mb1 = (const float*)d_in[10];
    const float* mw2 = (const float*)d_in[11];const float* mb2 = (const float*)d_in[12];
    float* out = (float*)d_out;

    const int N = GCN_N, E = GCN_E;
    const int* srcI = ei;
    const int* dstI = ei + E;

    char* ws = (char*)d_ws;
    float* ew     = (float*)ws;                      ws += (size_t)E * 4;
    int*   rank   = (int*)ws;                        ws += (size_t)E * 4;
    u64*   dc     = (u64*)(((uintptr_t)ws + 255) & ~(uintptr_t)255); ws = (char*)(dc + N);
    float* dinv   = (float*)ws;                      ws += (size_t)N * 4;
    float* invdeg = (float*)ws;                      ws += (size_t)N * 4;
    int*   offs   = (int*)ws;                        ws += (size_t)(N + 1) * 4;
    int*   bsum   = (int*)ws;                        ws += 64 * 4;
    int*   part   = (int*)ws;                        ws += (size_t)N * 4;
    int2*  csr    = (int2*)(((uintptr_t)ws + 255) & ~(uintptr_t)255); ws = (char*)(csr + E);
    ushort_t* h   = (ushort_t*)(((uintptr_t)ws + 255) & ~(uintptr_t)255);  // N*256 bf16
    ws = (char*)(h + (size_t)N * GCN_D);
    ushort_t* act = (ushort_t*)(((uintptr_t)ws + 255) & ~(uintptr_t)255);  // N*256 bf16
    ws = (char*)(act + (size_t)N * GCN_D);
    ushort_t* wtf = (ushort_t*)(((uintptr_t)ws + 255) & ~(uintptr_t)255);
    ushort_t* wtf_hi1 = wtf;            // 65536 each
    ushort_t* wtf_lo1 = wtf + 65536;
    ushort_t* wtf_hi2 = wtf + 2 * 65536;
    ushort_t* wtf_lo2 = wtf + 3 * 65536;
    ushort_t* wtf_hi3 = wtf + 4 * 65536;
    ushort_t* wtf_lo3 = wtf + 5 * 65536;

    init_kernel<<<(N + 255) / 256, 256, 0, stream>>>(dc, N);
    edge_mlp_kernel<<<(E + 255) / 256, 256, 0, stream>>>(attr, dstI, mw1, mb1, mw2, mb2,
                                                         ew, dc, rank, E);
    node_kernel<<<(N + 255) / 256, 256, 0, stream>>>(dc, dinv, invdeg, N);
    int nb = (N + 1023) / 1024;
    scan1_kernel<<<nb, 1024, 0, stream>>>(dc, part, bsum, N);
    scan2_kernel<<<1, 64, 0, stream>>>(bsum, nb);
    scan3_kernel<<<(N + 255) / 256, 256, 0, stream>>>(part, bsum, offs, N, E);
    scatter_kernel<<<(E + 255) / 256, 256, 0, stream>>>(srcI, dstI, ew, dinv, offs, rank,
                                                        csr, E);
    wconvert_kernel<<<8, 256, 0, stream>>>(W1, wtf_hi1, wtf_lo1);
    wconvert_kernel<<<8, 256, 0, stream>>>(W2, wtf_hi2, wtf_lo2);
    wconvert_kernel<<<8, 256, 0, stream>>>(W3, wtf_hi3, wtf_lo3);

    const int gemm_grid = (N + 63) / 64;
    const int spmm_grid = (N * 64 + 255) / 256;

    // layer 1: x fp32 -> h ; spmm -> act (bf16, relu)
    mfma_gemm_f32_kernel<<<gemm_grid, 256, 0, stream>>>(x, wtf_hi1, wtf_lo1, b1, h, N);
    spmm_kernel<1><<<spmm_grid, 256, 0, stream>>>(h, offs, csr, invdeg, act, N);
    // layer 2: act bf16 -> h ; spmm -> act
    mfma_gemm_bf16_kernel<<<gemm_grid, 256, 0, stream>>>(act, wtf_hi2, b2, h, N);
    spmm_kernel<1><<<spmm_grid, 256, 0, stream>>>(h, offs, csr, invdeg, act, N);
    // layer 3: act bf16 -> h ; spmm -> d_out (fp32, no relu)
    mfma_gemm_bf16_kernel<<<gemm_grid, 256, 0, stream>>>(act, wtf_hi3, b3, h, N);
    spmm_kernel<0><<<spmm_grid, 256, 0, stream>>>(h, offs, csr, invdeg, out, N);
}

// Round 9
// 335.249 us; speedup vs baseline: 1.1388x; 1.0629x over previous
//
#include <hip/hip_runtime.h>
#include <hip/hip_bf16.h>
#include <stdint.h>

#define GCN_N 50000
#define GCN_E 800000
#define GCN_D 256

typedef __attribute__((ext_vector_type(8))) short bf16x8;
typedef __attribute__((ext_vector_type(4))) float f32x4;
typedef unsigned short ushort_t;
typedef unsigned long long u64;

__device__ __forceinline__ float bf2f(ushort_t u) {
    return __uint_as_float(((unsigned)u) << 16);
}
__device__ __forceinline__ ushort_t f2bf(float f) {
    unsigned v = __float_as_uint(f);
    v += 0x7FFFu + ((v >> 16) & 1u);   // round-to-nearest-even
    return (ushort_t)(v >> 16);
}

// ---------------- preprocessing kernels ----------------

// dc[d] packs: count in bits [40..], sum(w) as 2^-32 fixed point in bits [0..40)
// atomic return value's count field = this edge's rank among its dst's edges.
__global__ void edge_mlp_kernel(const float* __restrict__ attr,
                                const int* __restrict__ dst,
                                const float* __restrict__ mw1, const float* __restrict__ mb1,
                                const float* __restrict__ mw2, const float* __restrict__ mb2,
                                float* __restrict__ ew, u64* __restrict__ dc,
                                int* __restrict__ rank, int e_count) {
    int e = blockIdx.x * blockDim.x + threadIdx.x;
    if (e >= e_count) return;
    float a = attr[e];
    float s = mb2[0];
#pragma unroll
    for (int j = 0; j < 8; ++j) {
        float hj = fmaf(a, mw1[j], mb1[j]);
        hj = fmaxf(hj, 0.0f);
        s = fmaf(hj, mw2[j], s);
    }
    float w = 1.0f / (1.0f + expf(-s));
    ew[e] = w;
    u64 pack = (1ull << 40) + (u64)((double)w * 4294967296.0);
    u64 old = atomicAdd(&dc[dst[e]], pack);
    rank[e] = (int)(old >> 40);
}

// block scan over counts + node normalization terms (fused)
__global__ __launch_bounds__(1024) void scan1_kernel(const u64* __restrict__ dc,
                                                     int* __restrict__ part,
                                                     int* __restrict__ bsum,
                                                     float* __restrict__ dinv,
                                                     float* __restrict__ invdeg, int n) {
    __shared__ int s[1024];
    int tid = threadIdx.x;
    int i = blockIdx.x * 1024 + tid;
    u64 dv = (i < n) ? dc[i] : 0ull;
    int v = (int)(dv >> 40);
    s[tid] = v;
    if (i < n) {
        float wsum = (float)((double)(dv & ((1ull << 40) - 1)) * (1.0 / 4294967296.0));
        float d = 1.0f + wsum;
        dinv[i] = rsqrtf(d);
        invdeg[i] = 1.0f / d;
    }
    __syncthreads();
#pragma unroll
    for (int d = 1; d < 1024; d <<= 1) {
        int t = (tid >= d) ? s[tid - d] : 0;
        __syncthreads();
        s[tid] += t;
        __syncthreads();
    }
    if (i < n) part[i] = s[tid] - v;  // exclusive within block
    if (tid == 1023) bsum[blockIdx.x] = s[1023];
}

// wave64 shuffle scan over block sums (nb <= 64)
__global__ void scan2_kernel(int* bsum, int nb) {
    int t = threadIdx.x;
    int orig = (t < nb) ? bsum[t] : 0;
    int v = orig;
#pragma unroll
    for (int d = 1; d < 64; d <<= 1) {
        int u = __shfl_up(v, d, 64);
        if (t >= d) v += u;
    }
    if (t < nb) bsum[t] = v - orig;   // exclusive
}

__global__ void scan3_kernel(const int* __restrict__ part, const int* __restrict__ bsum,
                             int* __restrict__ offs, int n, int e_total) {
    int i = blockIdx.x * blockDim.x + threadIdx.x;
    if (i < n) offs[i] = part[i] + bsum[i >> 10];
    if (i == 0) offs[n] = e_total;
}

// no atomics: position = offs[dst] + rank captured in edge_mlp
__global__ void scatter_kernel(const int* __restrict__ src, const int* __restrict__ dst,
                               const float* __restrict__ ew, const float* __restrict__ dinv,
                               const int* __restrict__ offs, const int* __restrict__ rank,
                               int2* __restrict__ csr, int e_count) {
    int e = blockIdx.x * blockDim.x + threadIdx.x;
    if (e >= e_count) return;
    int sN = src[e], dN = dst[e];
    int pos = offs[dN] + rank[e];
    float w = dinv[sN] * ew[e] * dinv[dN];
    csr[pos] = make_int2(sN, __float_as_int(w));
}

// ---------------- W -> bf16 hi/lo split in MFMA-fragment-major layout ----------------
// All 3 layers in one launch: grid 24, layer = blockIdx.x>>3, kt = blockIdx.x&7.

__global__ __launch_bounds__(256) void wconvert_kernel(
        const float* __restrict__ W1, const float* __restrict__ W2,
        const float* __restrict__ W3,
        ushort_t* __restrict__ wtf) {   // [3][2][65536] : layer, hi/lo
    __shared__ ushort_t lds_hi[32][256];
    __shared__ ushort_t lds_lo[32][256];
    const int layer = blockIdx.x >> 3;
    const int kt = blockIdx.x & 7;
    const float* W = (layer == 0) ? W1 : (layer == 1) ? W2 : W3;
    ushort_t* wtf_hi = wtf + (size_t)layer * 2 * 65536;
    ushort_t* wtf_lo = wtf_hi + 65536;
    const int tid = threadIdx.x;
    for (int c = 0; c < 32; ++c) {
        float f = W[(kt * 32 + c) * GCN_D + tid];
        unsigned u = __float_as_uint(f);
        ushort_t hi = (ushort_t)(u >> 16);               // truncation: exact residual
        float r = f - __uint_as_float(u & 0xFFFF0000u);
        lds_hi[c][tid] = hi;
        lds_lo[c][tid] = f2bf(r);
    }
    __syncthreads();
#pragma unroll
    for (int q = 0; q < 4; ++q) {
        int slot = q * 256 + tid;          // 0..1023 = nt*64 + lane
        int lane = slot & 63, nt = slot >> 6;
        int n = nt * 16 + (lane & 15);
        int kl = (lane >> 4) * 8;
        ushort_t h8[8], l8[8];
#pragma unroll
        for (int j = 0; j < 8; ++j) { h8[j] = lds_hi[kl + j][n]; l8[j] = lds_lo[kl + j][n]; }
        size_t o = ((size_t)(kt * 16 + nt) * 64 + lane) * 8;
#pragma unroll
        for (int j = 0; j < 8; ++j) { wtf_hi[o + j] = h8[j]; wtf_lo[o + j] = l8[j]; }
    }
}

// ---------------- MFMA GEMM (layer 1): fp32 x, split-precision, LDS-staged B ----------
// Block = 64 rows x 256 cols, 4 waves; wave = 16 rows x 256 cols (16 Ntiles, acc 64 VGPR).

__device__ __forceinline__ void split_f32x8(float4 f0, float4 f1, bf16x8& hi, bf16x8& lo) {
    float f[8] = {f0.x, f0.y, f0.z, f0.w, f1.x, f1.y, f1.z, f1.w};
#pragma unroll
    for (int i = 0; i < 8; ++i) {
        unsigned u = __float_as_uint(f[i]);
        hi[i] = (short)(u >> 16);
        float r = f[i] - __uint_as_float(u & 0xFFFF0000u);
        lo[i] = (short)f2bf(r);
    }
}

__global__ __launch_bounds__(256) void mfma_gemm_f32_kernel(
        const float* __restrict__ x,          // [n_rows][256] fp32
        const ushort_t* __restrict__ wtf_hi,  // fragment-major bf16 bits
        const ushort_t* __restrict__ wtf_lo,
        const float* __restrict__ bias,
        ushort_t* __restrict__ out_h,         // [n_rows][256] bf16
        int n_rows) {
    __shared__ ushort_t smem[4 * 16 * 264];   // 33792B; stage area = first 32KB
    const int tid  = threadIdx.x;
    const int lane = tid & 63;
    const int wv   = tid >> 6;
    const int r16  = lane & 15;
    const int kg   = lane >> 4;
    const int row0 = blockIdx.x * 64 + wv * 16;

    f32x4 acc[16];
#pragma unroll
    for (int nt = 0; nt < 16; ++nt) acc[nt] = (f32x4){0.f, 0.f, 0.f, 0.f};

    const int arow = row0 + r16;
    const float* ap = (arow < n_rows) ? &x[(size_t)arow * GCN_D + kg * 8] : nullptr;
    bf16x8* sH = (bf16x8*)smem;        // 1024 fragments (16KB)
    bf16x8* sL = ((bf16x8*)smem) + 1024;

#pragma unroll 1
    for (int kt = 0; kt < 8; ++kt) {
        float4 f0 = make_float4(0.f, 0.f, 0.f, 0.f), f1 = f0;
        if (ap) {
            f0 = *(const float4*)(ap + kt * 32);
            f1 = *(const float4*)(ap + kt * 32 + 4);
        }
        const bf16x8* gh = (const bf16x8*)wtf_hi + (size_t)kt * 1024;
        const bf16x8* gl = (const bf16x8*)wtf_lo + (size_t)kt * 1024;
        bf16x8 t0 = gh[tid], t1 = gh[256 + tid], t2 = gh[512 + tid], t3 = gh[768 + tid];
        bf16x8 u0 = gl[tid], u1 = gl[256 + tid], u2 = gl[512 + tid], u3 = gl[768 + tid];
        sH[tid] = t0; sH[256 + tid] = t1; sH[512 + tid] = t2; sH[768 + tid] = t3;
        sL[tid] = u0; sL[256 + tid] = u1; sL[512 + tid] = u2; sL[768 + tid] = u3;
        bf16x8 a_hi, a_lo;
        split_f32x8(f0, f1, a_hi, a_lo);
        __syncthreads();
#pragma unroll
        for (int nt = 0; nt < 16; ++nt) {
            bf16x8 bh = sH[nt * 64 + lane];
            bf16x8 bl = sL[nt * 64 + lane];
            acc[nt] = __builtin_amdgcn_mfma_f32_16x16x32_bf16(a_hi, bh, acc[nt], 0, 0, 0);
            acc[nt] = __builtin_amdgcn_mfma_f32_16x16x32_bf16(a_lo, bh, acc[nt], 0, 0, 0);
            acc[nt] = __builtin_amdgcn_mfma_f32_16x16x32_bf16(a_hi, bl, acc[nt], 0, 0, 0);
        }
        __syncthreads();
    }

    // epilogue: reuse smem. C layout: col = lane&15, row = (lane>>4)*4 + reg
    ushort_t* my = smem + wv * (16 * 264);
#pragma unroll
    for (int nt = 0; nt < 16; ++nt) {
        float bv = bias[nt * 16 + r16];
#pragma unroll
        for (int r = 0; r < 4; ++r)
            my[(kg * 4 + r) * 264 + nt * 16 + r16] = f2bf(acc[nt][r] + bv);
    }
#pragma unroll 4
    for (int r = 0; r < 16; ++r) {
        int row = row0 + r;
        if (row < n_rows) {
            ushort4 v = *(ushort4*)&my[r * 264 + lane * 4];
            *(ushort4*)&out_h[(size_t)row * GCN_D + lane * 4] = v;
        }
    }
}

// ---------------- MFMA GEMM (layers 2,3): bf16 A, W_hi only, LDS-staged B ------------
// Stages a kt-PAIR (32KB) per barrier pair -> half the barriers of per-kt staging.

__global__ __launch_bounds__(256) void mfma_gemm_bf16_kernel(
        const ushort_t* __restrict__ a_in,    // [n_rows][256] bf16
        const ushort_t* __restrict__ wtf_hi,
        const float* __restrict__ bias,
        ushort_t* __restrict__ out_h,         // [n_rows][256] bf16
        int n_rows) {
    __shared__ ushort_t smem[4 * 16 * 264];   // 33792B >= 32KB stage area
    const int tid  = threadIdx.x;
    const int lane = tid & 63;
    const int wv   = tid >> 6;
    const int r16  = lane & 15;
    const int kg   = lane >> 4;
    const int row0 = blockIdx.x * 64 + wv * 16;

    f32x4 acc[16];
#pragma unroll
    for (int nt = 0; nt < 16; ++nt) acc[nt] = (f32x4){0.f, 0.f, 0.f, 0.f};

    const int arow = row0 + r16;
    const ushort_t* ap = (arow < n_rows) ? &a_in[(size_t)arow * GCN_D + kg * 8] : nullptr;
    bf16x8* sH = (bf16x8*)smem;               // 2048 fragments (32KB)

#pragma unroll 1
    for (int kp = 0; kp < 4; ++kp) {          // kt pair
        const bf16x8* gh = (const bf16x8*)wtf_hi + (size_t)kp * 2048;
        bf16x8 t[8];
#pragma unroll
        for (int j = 0; j < 8; ++j) t[j] = gh[j * 256 + tid];
        bf16x8 a0 = (bf16x8){0,0,0,0,0,0,0,0}, a1 = a0;
        if (ap) {
            a0 = *(const bf16x8*)(ap + (kp * 2) * 32);
            a1 = *(const bf16x8*)(ap + (kp * 2 + 1) * 32);
        }
#pragma unroll
        for (int j = 0; j < 8; ++j) sH[j * 256 + tid] = t[j];
        __syncthreads();
#pragma unroll
        for (int nt = 0; nt < 16; ++nt) {
            bf16x8 bh0 = sH[nt * 64 + lane];
            bf16x8 bh1 = sH[1024 + nt * 64 + lane];
            acc[nt] = __builtin_amdgcn_mfma_f32_16x16x32_bf16(a0, bh0, acc[nt], 0, 0, 0);
            acc[nt] = __builtin_amdgcn_mfma_f32_16x16x32_bf16(a1, bh1, acc[nt], 0, 0, 0);
        }
        __syncthreads();
    }

    ushort_t* my = smem + wv * (16 * 264);
#pragma unroll
    for (int nt = 0; nt < 16; ++nt) {
        float bv = bias[nt * 16 + r16];
#pragma unroll
        for (int r = 0; r < 4; ++r)
            my[(kg * 4 + r) * 264 + nt * 16 + r16] = f2bf(acc[nt][r] + bv);
    }
#pragma unroll 4
    for (int r = 0; r < 16; ++r) {
        int row = row0 + r;
        if (row < n_rows) {
            ushort4 v = *(ushort4*)&my[r * 264 + lane * 4];
            *(ushort4*)&out_h[(size_t)row * GCN_D + lane * 4] = v;
        }
    }
}

// ---------------- SpMM: agg = A_norm*h + diag(1/deg)*h ----------------
// one wave per node; bf16 gathers (8B/lane), CSR packed int2, 8 gathers in flight
// (16-deep tried in R8: VGPR 40, occupancy 48%, slower. 8 is the sweet spot.)

template <int OUT_BF16>
__global__ __launch_bounds__(256) void spmm_kernel(const ushort_t* __restrict__ h,
                                                   const int* __restrict__ offs,
                                                   const int2* __restrict__ csr,
                                                   const float* __restrict__ invdeg,
                                                   void* __restrict__ outp, int n) {
    int wid = (blockIdx.x * blockDim.x + threadIdx.x) >> 6;
    int lane = threadIdx.x & 63;
    if (wid >= n) return;
    const ushort4* h4 = (const ushort4*)h;
    ushort4 sv = h4[(size_t)wid * 64 + lane];
    float sw = invdeg[wid];
    float4 acc;
    acc.x = bf2f(sv.x) * sw; acc.y = bf2f(sv.y) * sw;
    acc.z = bf2f(sv.z) * sw; acc.w = bf2f(sv.w) * sw;
    int e0 = offs[wid], e1 = offs[wid + 1];
    int k = e0;
    for (; k + 8 <= e1; k += 8) {
        int2 ee[8]; ushort4 vv[8];
#pragma unroll
        for (int u = 0; u < 8; ++u) ee[u] = csr[k + u];
#pragma unroll
        for (int u = 0; u < 8; ++u) vv[u] = h4[(size_t)ee[u].x * 64 + lane];
#pragma unroll
        for (int u = 0; u < 8; ++u) {
            float w = __int_as_float(ee[u].y);
            acc.x = fmaf(w, bf2f(vv[u].x), acc.x);
            acc.y = fmaf(w, bf2f(vv[u].y), acc.y);
            acc.z = fmaf(w, bf2f(vv[u].z), acc.z);
            acc.w = fmaf(w, bf2f(vv[u].w), acc.w);
        }
    }
    for (; k < e1; ++k) {
        int2 e = csr[k];
        float w = __int_as_float(e.y);
        ushort4 hv = h4[(size_t)e.x * 64 + lane];
        acc.x = fmaf(w, bf2f(hv.x), acc.x);
        acc.y = fmaf(w, bf2f(hv.y), acc.y);
        acc.z = fmaf(w, bf2f(hv.z), acc.z);
        acc.w = fmaf(w, bf2f(hv.w), acc.w);
    }
    if (OUT_BF16) {
        ushort4 o;
        o.x = f2bf(fmaxf(acc.x, 0.f));
        o.y = f2bf(fmaxf(acc.y, 0.f));
        o.z = f2bf(fmaxf(acc.z, 0.f));
        o.w = f2bf(fmaxf(acc.w, 0.f));
        ((ushort4*)outp)[(size_t)wid * 64 + lane] = o;
    } else {
        ((float4*)outp)[(size_t)wid * 64 + lane] = acc;
    }
}

// ---------------- launch ----------------

extern "C" void kernel_launch(void* const* d_in, const int* in_sizes, int n_in,
                              void* d_out, int out_size, void* d_ws, size_t ws_size,
                              hipStream_t stream) {
    const float* x    = (const float*)d_in[0];
    const int*   ei   = (const int*)d_in[1];
    const float* attr = (const float*)d_in[2];
    const float* W1 = (const float*)d_in[3];  const float* b1 = (const float*)d_in[4];
    const float* W2 = (const float*)d_in[5];  const float* b2 = (const float*)d_in[6];
    const float* W3 = (const float*)d_in[7];  const float* b3 = (const float*)d_in[8];
    const float* mw1 = (const float*)d_in[9]; const float* mb1 = (const float*)d_in[10];
    const float* mw2 = (const float*)d_in[11];const float* mb2 = (const float*)d_in[12];
    float* out = (float*)d_out;

    const int N = GCN_N, E = GCN_E;
    const int* srcI = ei;
    const int* dstI = ei + E;

    char* ws = (char*)d_ws;
    float* ew     = (float*)ws;                      ws += (size_t)E * 4;
    int*   rank   = (int*)ws;                        ws += (size_t)E * 4;
    u64*   dc     = (u64*)(((uintptr_t)ws + 255) & ~(uintptr_t)255); ws = (char*)(dc + N);
    float* dinv   = (float*)ws;                      ws += (size_t)N * 4;
    float* invdeg = (float*)ws;                      ws += (size_t)N * 4;
    int*   offs   = (int*)ws;                        ws += (size_t)(N + 1) * 4;
    int*   bsum   = (int*)ws;                        ws += 64 * 4;
    int*   part   = (int*)ws;                        ws += (size_t)N * 4;
    int2*  csr    = (int2*)(((uintptr_t)ws + 255) & ~(uintptr_t)255); ws = (char*)(csr + E);
    ushort_t* h   = (ushort_t*)(((uintptr_t)ws + 255) & ~(uintptr_t)255);  // N*256 bf16
    ws = (char*)(h + (size_t)N * GCN_D);
    ushort_t* act = (ushort_t*)(((uintptr_t)ws + 255) & ~(uintptr_t)255);  // N*256 bf16
    ws = (char*)(act + (size_t)N * GCN_D);
    ushort_t* wtf = (ushort_t*)(((uintptr_t)ws + 255) & ~(uintptr_t)255);  // [3][2][65536]
    ushort_t* wtf_hi1 = wtf;
    ushort_t* wtf_lo1 = wtf + 65536;
    ushort_t* wtf_hi2 = wtf + 2 * 65536;
    ushort_t* wtf_hi3 = wtf + 4 * 65536;

    hipMemsetAsync(dc, 0, (size_t)N * sizeof(u64), stream);
    edge_mlp_kernel<<<(E + 255) / 256, 256, 0, stream>>>(attr, dstI, mw1, mb1, mw2, mb2,
                                                         ew, dc, rank, E);
    int nb = (N + 1023) / 1024;
    scan1_kernel<<<nb, 1024, 0, stream>>>(dc, part, bsum, dinv, invdeg, N);
    scan2_kernel<<<1, 64, 0, stream>>>(bsum, nb);
    scan3_kernel<<<(N + 255) / 256, 256, 0, stream>>>(part, bsum, offs, N, E);
    scatter_kernel<<<(E + 255) / 256, 256, 0, stream>>>(srcI, dstI, ew, dinv, offs, rank,
                                                        csr, E);
    wconvert_kernel<<<24, 256, 0, stream>>>(W1, W2, W3, wtf);

    const int gemm_grid = (N + 63) / 64;
    const int spmm_grid = (N * 64 + 255) / 256;

    // layer 1: x fp32 -> h ; spmm -> act (bf16, relu)
    mfma_gemm_f32_kernel<<<gemm_grid, 256, 0, stream>>>(x, wtf_hi1, wtf_lo1, b1, h, N);
    spmm_kernel<1><<<spmm_grid, 256, 0, stream>>>(h, offs, csr, invdeg, act, N);
    // layer 2: act bf16 -> h ; spmm -> act
    mfma_gemm_bf16_kernel<<<gemm_grid, 256, 0, stream>>>(act, wtf_hi2, b2, h, N);
    spmm_kernel<1><<<spmm_grid, 256, 0, stream>>>(h, offs, csr, invdeg, act, N);
    // layer 3: act bf16 -> h ; spmm -> d_out (fp32, no relu)
    mfma_gemm_bf16_kernel<<<gemm_grid, 256, 0, stream>>>(act, wtf_hi3, b3, h, N);
    spmm_kernel<0><<<spmm_grid, 256, 0, stream>>>(h, offs, csr, invdeg, out, N);
}

// Round 10
// 326.823 us; speedup vs baseline: 1.1682x; 1.0258x over previous
//
#include <hip/hip_runtime.h>
#include <hip/hip_bf16.h>
#include <stdint.h>

#define GCN_N 50000
#define GCN_E 800000
#define GCN_D 256

#define GEMM_BLOCKS ((GCN_N + 63) / 64)     // 782
#define EDGE_BLOCKS ((GCN_E + 255) / 256)   // 3125

typedef __attribute__((ext_vector_type(8))) short bf16x8;
typedef __attribute__((ext_vector_type(4))) float f32x4;
typedef unsigned short ushort_t;
typedef unsigned long long u64;

__device__ __forceinline__ float bf2f(ushort_t u) {
    return __uint_as_float(((unsigned)u) << 16);
}
__device__ __forceinline__ ushort_t f2bf(float f) {
    unsigned v = __float_as_uint(f);
    v += 0x7FFFu + ((v >> 16) & 1u);   // round-to-nearest-even
    return (ushort_t)(v >> 16);
}

__device__ __forceinline__ void split_f32x8(float4 f0, float4 f1, bf16x8& hi, bf16x8& lo) {
    float f[8] = {f0.x, f0.y, f0.z, f0.w, f1.x, f1.y, f1.z, f1.w};
#pragma unroll
    for (int i = 0; i < 8; ++i) {
        unsigned u = __float_as_uint(f[i]);
        hi[i] = (short)(u >> 16);
        float r = f[i] - __uint_as_float(u & 0xFFFF0000u);
        lo[i] = (short)f2bf(r);
    }
}

// W -> bf16 hi/lo fragment-major conversion body (one kt-block of one layer)
__device__ __forceinline__ void wconv_body(const float* __restrict__ W, int kt, int tid,
                                           ushort_t* __restrict__ wtf_hi,
                                           ushort_t* __restrict__ wtf_lo,
                                           ushort_t* smem) {
    ushort_t (*lds_hi)[256] = (ushort_t(*)[256])smem;
    ushort_t (*lds_lo)[256] = (ushort_t(*)[256])(smem + 8192);
    for (int c = 0; c < 32; ++c) {
        float f = W[(kt * 32 + c) * GCN_D + tid];
        unsigned u = __float_as_uint(f);
        lds_hi[c][tid] = (ushort_t)(u >> 16);              // truncation: exact residual
        float r = f - __uint_as_float(u & 0xFFFF0000u);
        lds_lo[c][tid] = f2bf(r);
    }
    __syncthreads();
#pragma unroll
    for (int q = 0; q < 4; ++q) {
        int slot = q * 256 + tid;          // 0..1023 = nt*64 + lane
        int lane = slot & 63, nt = slot >> 6;
        int n = nt * 16 + (lane & 15);
        int kl = (lane >> 4) * 8;
        ushort_t h8[8], l8[8];
#pragma unroll
        for (int j = 0; j < 8; ++j) { h8[j] = lds_hi[kl + j][n]; l8[j] = lds_lo[kl + j][n]; }
        size_t o = ((size_t)(kt * 16 + nt) * 64 + lane) * 8;
#pragma unroll
        for (int j = 0; j < 8; ++j) { wtf_hi[o + j] = h8[j]; wtf_lo[o + j] = l8[j]; }
    }
}

// layer-1 W conversion: must precede fused1 (whose gemm blocks read it).
__global__ __launch_bounds__(256) void wconv1_kernel(const float* __restrict__ W,
                                                     ushort_t* __restrict__ wtf) {
    __shared__ ushort_t smem[16384];
    wconv_body(W, blockIdx.x, threadIdx.x, wtf, wtf + 65536, smem);
}

// ================= fused: gemm_f32(layer1) | edge_mlp | wconvert(L2,L3) ==========
// Independent work co-scheduled in one dispatch: MFMA-bound gemm waves overlap
// atomic-latency-bound edge waves (separate pipes overlap fully, m114).

__global__ __launch_bounds__(256) void fused1_kernel(
        const float* __restrict__ x, const ushort_t* __restrict__ wtf_hi1,
        const ushort_t* __restrict__ wtf_lo1, const float* __restrict__ b1,
        ushort_t* __restrict__ out_h,
        const float* __restrict__ attr, const int* __restrict__ dst,
        const float* __restrict__ mw1, const float* __restrict__ mb1,
        const float* __restrict__ mw2, const float* __restrict__ mb2,
        float* __restrict__ ew, u64* __restrict__ dc, int* __restrict__ rank,
        const float* __restrict__ W2, const float* __restrict__ W3,
        ushort_t* __restrict__ wtf) {
    __shared__ ushort_t smem[4 * 16 * 264];   // 33792B
    const int b = blockIdx.x;
    const int tid = threadIdx.x;

    if (b < GEMM_BLOCKS) {
        // ---------- gemm_f32: 64 rows x 256 cols, split-precision, LDS-staged B --------
        const int lane = tid & 63;
        const int wv   = tid >> 6;
        const int r16  = lane & 15;
        const int kg   = lane >> 4;
        const int row0 = b * 64 + wv * 16;

        f32x4 acc[16];
#pragma unroll
        for (int nt = 0; nt < 16; ++nt) acc[nt] = (f32x4){0.f, 0.f, 0.f, 0.f};

        const int arow = row0 + r16;
        const float* ap = (arow < GCN_N) ? &x[(size_t)arow * GCN_D + kg * 8] : nullptr;
        bf16x8* sH = (bf16x8*)smem;
        bf16x8* sL = ((bf16x8*)smem) + 1024;

#pragma unroll 1
        for (int kt = 0; kt < 8; ++kt) {
            float4 f0 = make_float4(0.f, 0.f, 0.f, 0.f), f1 = f0;
            if (ap) {
                f0 = *(const float4*)(ap + kt * 32);
                f1 = *(const float4*)(ap + kt * 32 + 4);
            }
            const bf16x8* gh = (const bf16x8*)wtf_hi1 + (size_t)kt * 1024;
            const bf16x8* gl = (const bf16x8*)wtf_lo1 + (size_t)kt * 1024;
            bf16x8 t0 = gh[tid], t1 = gh[256 + tid], t2 = gh[512 + tid], t3 = gh[768 + tid];
            bf16x8 u0 = gl[tid], u1 = gl[256 + tid], u2 = gl[512 + tid], u3 = gl[768 + tid];
            sH[tid] = t0; sH[256 + tid] = t1; sH[512 + tid] = t2; sH[768 + tid] = t3;
            sL[tid] = u0; sL[256 + tid] = u1; sL[512 + tid] = u2; sL[768 + tid] = u3;
            bf16x8 a_hi, a_lo;
            split_f32x8(f0, f1, a_hi, a_lo);
            __syncthreads();
#pragma unroll
            for (int nt = 0; nt < 16; ++nt) {
                bf16x8 bh = sH[nt * 64 + lane];
                bf16x8 bl = sL[nt * 64 + lane];
                acc[nt] = __builtin_amdgcn_mfma_f32_16x16x32_bf16(a_hi, bh, acc[nt], 0, 0, 0);
                acc[nt] = __builtin_amdgcn_mfma_f32_16x16x32_bf16(a_lo, bh, acc[nt], 0, 0, 0);
                acc[nt] = __builtin_amdgcn_mfma_f32_16x16x32_bf16(a_hi, bl, acc[nt], 0, 0, 0);
            }
            __syncthreads();
        }

        ushort_t* my = smem + wv * (16 * 264);
#pragma unroll
        for (int nt = 0; nt < 16; ++nt) {
            float bv = b1[nt * 16 + r16];
#pragma unroll
            for (int r = 0; r < 4; ++r)
                my[(kg * 4 + r) * 264 + nt * 16 + r16] = f2bf(acc[nt][r] + bv);
        }
#pragma unroll 4
        for (int r = 0; r < 16; ++r) {
            int row = row0 + r;
            if (row < GCN_N) {
                ushort4 v = *(ushort4*)&my[r * 264 + lane * 4];
                *(ushort4*)&out_h[(size_t)row * GCN_D + lane * 4] = v;
            }
        }
    } else if (b < GEMM_BLOCKS + EDGE_BLOCKS) {
        // ---------- edge mlp + packed histogram atomic (rank = returned count) --------
        int e = (b - GEMM_BLOCKS) * 256 + tid;
        if (e >= GCN_E) return;
        float a = attr[e];
        float s = mb2[0];
#pragma unroll
        for (int j = 0; j < 8; ++j) {
            float hj = fmaf(a, mw1[j], mb1[j]);
            hj = fmaxf(hj, 0.0f);
            s = fmaf(hj, mw2[j], s);
        }
        float w = 1.0f / (1.0f + expf(-s));
        ew[e] = w;
        u64 pack = (1ull << 40) + (u64)((double)w * 4294967296.0);
        u64 old = atomicAdd(&dc[dst[e]], pack);
        rank[e] = (int)(old >> 40);
    } else {
        // ---------- wconvert layers 2,3 (16 blocks) ----------
        const int wb = b - GEMM_BLOCKS - EDGE_BLOCKS;   // 0..15
        const int layer = 1 + (wb >> 3);                // 1 or 2
        const int kt = wb & 7;
        const float* W = (layer == 1) ? W2 : W3;
        ushort_t* wtf_hi = wtf + (size_t)layer * 2 * 65536;
        wconv_body(W, kt, tid, wtf_hi, wtf_hi + 65536, smem);
    }
}

// ---------------- preprocessing (post-fused) ----------------

__global__ __launch_bounds__(1024) void scan1_kernel(const u64* __restrict__ dc,
                                                     int* __restrict__ part,
                                                     int* __restrict__ bsum,
                                                     float* __restrict__ dinv,
                                                     float* __restrict__ invdeg, int n) {
    __shared__ int s[1024];
    int tid = threadIdx.x;
    int i = blockIdx.x * 1024 + tid;
    u64 dv = (i < n) ? dc[i] : 0ull;
    int v = (int)(dv >> 40);
    s[tid] = v;
    if (i < n) {
        float wsum = (float)((double)(dv & ((1ull << 40) - 1)) * (1.0 / 4294967296.0));
        float d = 1.0f + wsum;
        dinv[i] = rsqrtf(d);
        invdeg[i] = 1.0f / d;
    }
    __syncthreads();
#pragma unroll
    for (int d = 1; d < 1024; d <<= 1) {
        int t = (tid >= d) ? s[tid - d] : 0;
        __syncthreads();
        s[tid] += t;
        __syncthreads();
    }
    if (i < n) part[i] = s[tid] - v;  // exclusive within block
    if (tid == 1023) bsum[blockIdx.x] = s[1023];
}

__global__ void scan2_kernel(int* bsum, int nb) {
    int t = threadIdx.x;
    int orig = (t < nb) ? bsum[t] : 0;
    int v = orig;
#pragma unroll
    for (int d = 1; d < 64; d <<= 1) {
        int u = __shfl_up(v, d, 64);
        if (t >= d) v += u;
    }
    if (t < nb) bsum[t] = v - orig;   // exclusive
}

__global__ void scan3_kernel(const int* __restrict__ part, const int* __restrict__ bsum,
                             int* __restrict__ offs, int n, int e_total) {
    int i = blockIdx.x * blockDim.x + threadIdx.x;
    if (i < n) offs[i] = part[i] + bsum[i >> 10];
    if (i == 0) offs[n] = e_total;
}

__global__ void scatter_kernel(const int* __restrict__ src, const int* __restrict__ dst,
                               const float* __restrict__ ew, const float* __restrict__ dinv,
                               const int* __restrict__ offs, const int* __restrict__ rank,
                               int2* __restrict__ csr, int e_count) {
    int e = blockIdx.x * blockDim.x + threadIdx.x;
    if (e >= e_count) return;
    int sN = src[e], dN = dst[e];
    int pos = offs[dN] + rank[e];
    float w = dinv[sN] * ew[e] * dinv[dN];
    csr[pos] = make_int2(sN, __float_as_int(w));
}

// ---------------- MFMA GEMM (layers 2,3): bf16 A, W_hi only, LDS-staged B ------------

__global__ __launch_bounds__(256) void mfma_gemm_bf16_kernel(
        const ushort_t* __restrict__ a_in,
        const ushort_t* __restrict__ wtf_hi,
        const float* __restrict__ bias,
        ushort_t* __restrict__ out_h,
        int n_rows) {
    __shared__ ushort_t smem[4 * 16 * 264];
    const int tid  = threadIdx.x;
    const int lane = tid & 63;
    const int wv   = tid >> 6;
    const int r16  = lane & 15;
    const int kg   = lane >> 4;
    const int row0 = blockIdx.x * 64 + wv * 16;

    f32x4 acc[16];
#pragma unroll
    for (int nt = 0; nt < 16; ++nt) acc[nt] = (f32x4){0.f, 0.f, 0.f, 0.f};

    const int arow = row0 + r16;
    const ushort_t* ap = (arow < n_rows) ? &a_in[(size_t)arow * GCN_D + kg * 8] : nullptr;
    bf16x8* sH = (bf16x8*)smem;

#pragma unroll 1
    for (int kp = 0; kp < 4; ++kp) {
        const bf16x8* gh = (const bf16x8*)wtf_hi + (size_t)kp * 2048;
        bf16x8 t[8];
#pragma unroll
        for (int j = 0; j < 8; ++j) t[j] = gh[j * 256 + tid];
        bf16x8 a0 = (bf16x8){0,0,0,0,0,0,0,0}, a1 = a0;
        if (ap) {
            a0 = *(const bf16x8*)(ap + (kp * 2) * 32);
            a1 = *(const bf16x8*)(ap + (kp * 2 + 1) * 32);
        }
#pragma unroll
        for (int j = 0; j < 8; ++j) sH[j * 256 + tid] = t[j];
        __syncthreads();
#pragma unroll
        for (int nt = 0; nt < 16; ++nt) {
            bf16x8 bh0 = sH[nt * 64 + lane];
            bf16x8 bh1 = sH[1024 + nt * 64 + lane];
            acc[nt] = __builtin_amdgcn_mfma_f32_16x16x32_bf16(a0, bh0, acc[nt], 0, 0, 0);
            acc[nt] = __builtin_amdgcn_mfma_f32_16x16x32_bf16(a1, bh1, acc[nt], 0, 0, 0);
        }
        __syncthreads();
    }

    ushort_t* my = smem + wv * (16 * 264);
#pragma unroll
    for (int nt = 0; nt < 16; ++nt) {
        float bv = bias[nt * 16 + r16];
#pragma unroll
        for (int r = 0; r < 4; ++r)
            my[(kg * 4 + r) * 264 + nt * 16 + r16] = f2bf(acc[nt][r] + bv);
    }
#pragma unroll 4
    for (int r = 0; r < 16; ++r) {
        int row = row0 + r;
        if (row < n_rows) {
            ushort4 v = *(ushort4*)&my[r * 264 + lane * 4];
            *(ushort4*)&out_h[(size_t)row * GCN_D + lane * 4] = v;
        }
    }
}

// ---------------- SpMM: agg = A_norm*h + diag(1/deg)*h ----------------

template <int OUT_BF16>
__global__ __launch_bounds__(256) void spmm_kernel(const ushort_t* __restrict__ h,
                                                   const int* __restrict__ offs,
                                                   const int2* __restrict__ csr,
                                                   const float* __restrict__ invdeg,
                                                   void* __restrict__ outp, int n) {
    int wid = (blockIdx.x * blockDim.x + threadIdx.x) >> 6;
    int lane = threadIdx.x & 63;
    if (wid >= n) return;
    const ushort4* h4 = (const ushort4*)h;
    ushort4 sv = h4[(size_t)wid * 64 + lane];
    float sw = invdeg[wid];
    float4 acc;
    acc.x = bf2f(sv.x) * sw; acc.y = bf2f(sv.y) * sw;
    acc.z = bf2f(sv.z) * sw; acc.w = bf2f(sv.w) * sw;
    int e0 = offs[wid], e1 = offs[wid + 1];
    int k = e0;
    for (; k + 8 <= e1; k += 8) {
        int2 ee[8]; ushort4 vv[8];
#pragma unroll
        for (int u = 0; u < 8; ++u) ee[u] = csr[k + u];
#pragma unroll
        for (int u = 0; u < 8; ++u) vv[u] = h4[(size_t)ee[u].x * 64 + lane];
#pragma unroll
        for (int u = 0; u < 8; ++u) {
            float w = __int_as_float(ee[u].y);
            acc.x = fmaf(w, bf2f(vv[u].x), acc.x);
            acc.y = fmaf(w, bf2f(vv[u].y), acc.y);
            acc.z = fmaf(w, bf2f(vv[u].z), acc.z);
            acc.w = fmaf(w, bf2f(vv[u].w), acc.w);
        }
    }
    for (; k < e1; ++k) {
        int2 e = csr[k];
        float w = __int_as_float(e.y);
        ushort4 hv = h4[(size_t)e.x * 64 + lane];
        acc.x = fmaf(w, bf2f(hv.x), acc.x);
        acc.y = fmaf(w, bf2f(hv.y), acc.y);
        acc.z = fmaf(w, bf2f(hv.z), acc.z);
        acc.w = fmaf(w, bf2f(hv.w), acc.w);
    }
    if (OUT_BF16) {
        ushort4 o;
        o.x = f2bf(fmaxf(acc.x, 0.f));
        o.y = f2bf(fmaxf(acc.y, 0.f));
        o.z = f2bf(fmaxf(acc.z, 0.f));
        o.w = f2bf(fmaxf(acc.w, 0.f));
        ((ushort4*)outp)[(size_t)wid * 64 + lane] = o;
    } else {
        ((float4*)outp)[(size_t)wid * 64 + lane] = acc;
    }
}

// ---------------- launch ----------------

extern "C" void kernel_launch(void* const* d_in, const int* in_sizes, int n_in,
                              void* d_out, int out_size, void* d_ws, size_t ws_size,
                              hipStream_t stream) {
    const float* x    = (const float*)d_in[0];
    const int*   ei   = (const int*)d_in[1];
    const float* attr = (const float*)d_in[2];
    const float* W1 = (const float*)d_in[3];  const float* b1 = (const float*)d_in[4];
    const float* W2 = (const float*)d_in[5];  const float* b2 = (const float*)d_in[6];
    const float* W3 = (const float*)d_in[7];  const float* b3 = (const float*)d_in[8];
    const float* mw1 = (const float*)d_in[9]; const float* mb1 = (const float*)d_in[10];
    const float* mw2 = (const float*)d_in[11];const float* mb2 = (const float*)d_in[12];
    float* out = (float*)d_out;

    const int N = GCN_N, E = GCN_E;
    const int* srcI = ei;
    const int* dstI = ei + E;

    char* ws = (char*)d_ws;
    float* ew     = (float*)ws;                      ws += (size_t)E * 4;
    int*   rank   = (int*)ws;                        ws += (size_t)E * 4;
    u64*   dc     = (u64*)(((uintptr_t)ws + 255) & ~(uintptr_t)255); ws = (char*)(dc + N);
    float* dinv   = (float*)ws;                      ws += (size_t)N * 4;
    float* invdeg = (float*)ws;                      ws += (size_t)N * 4;
    int*   offs   = (int*)ws;                        ws += (size_t)(N + 1) * 4;
    int*   bsum   = (int*)ws;                        ws += 64 * 4;
    int*   part   = (int*)ws;                        ws += (size_t)N * 4;
    int2*  csr    = (int2*)(((uintptr_t)ws + 255) & ~(uintptr_t)255); ws = (char*)(csr + E);
    ushort_t* h   = (ushort_t*)(((uintptr_t)ws + 255) & ~(uintptr_t)255);  // N*256 bf16
    ws = (char*)(h + (size_t)N * GCN_D);
    ushort_t* act = (ushort_t*)(((uintptr_t)ws + 255) & ~(uintptr_t)255);  // N*256 bf16
    ws = (char*)(act + (size_t)N * GCN_D);
    ushort_t* wtf = (ushort_t*)(((uintptr_t)ws + 255) & ~(uintptr_t)255);  // [3][2][65536]
    ushort_t* wtf_hi1 = wtf;
    ushort_t* wtf_lo1 = wtf + 65536;
    ushort_t* wtf_hi2 = wtf + 2 * 65536;
    ushort_t* wtf_hi3 = wtf + 4 * 65536;

    hipMemsetAsync(dc, 0, (size_t)N * sizeof(u64), stream);
    wconv1_kernel<<<8, 256, 0, stream>>>(W1, wtf);
    fused1_kernel<<<GEMM_BLOCKS + EDGE_BLOCKS + 16, 256, 0, stream>>>(
        x, wtf_hi1, wtf_lo1, b1, h,
        attr, dstI, mw1, mb1, mw2, mb2, ew, dc, rank,
        W2, W3, wtf);
    int nb = (N + 1023) / 1024;
    scan1_kernel<<<nb, 1024, 0, stream>>>(dc, part, bsum, dinv, invdeg, N);
    scan2_kernel<<<1, 64, 0, stream>>>(bsum, nb);
    scan3_kernel<<<(N + 255) / 256, 256, 0, stream>>>(part, bsum, offs, N, E);
    scatter_kernel<<<(E + 255) / 256, 256, 0, stream>>>(srcI, dstI, ew, dinv, offs, rank,
                                                        csr, E);

    const int gemm_grid = (N + 63) / 64;
    const int spmm_grid = (N * 64 + 255) / 256;

    // layer 1 spmm (h computed inside fused1)
    spmm_kernel<1><<<spmm_grid, 256, 0, stream>>>(h, offs, csr, invdeg, act, N);
    // layer 2
    mfma_gemm_bf16_kernel<<<gemm_grid, 256, 0, stream>>>(act, wtf_hi2, b2, h, N);
    spmm_kernel<1><<<spmm_grid, 256, 0, stream>>>(h, offs, csr, invdeg, act, N);
    // layer 3
    mfma_gemm_bf16_kernel<<<gemm_grid, 256, 0, stream>>>(act, wtf_hi3, b3, h, N);
    spmm_kernel<0><<<spmm_grid, 256, 0, stream>>>(h, offs, csr, invdeg, out, N);
}

// Round 12
// 315.549 us; speedup vs baseline: 1.2099x; 1.0357x over previous
//
#include <hip/hip_runtime.h>
#include <hip/hip_bf16.h>
#include <stdint.h>

#define GCN_N 50000
#define GCN_E 800000
#define GCN_D 256

#define GEMM_BLOCKS ((GCN_N + 63) / 64)     // 782
#define EDGE_BLOCKS ((GCN_E + 255) / 256)   // 3125

typedef __attribute__((ext_vector_type(8))) short bf16x8;
typedef __attribute__((ext_vector_type(4))) float f32x4;
typedef unsigned short ushort_t;
typedef unsigned long long u64;

__device__ __forceinline__ float bf2f(ushort_t u) {
    return __uint_as_float(((unsigned)u) << 16);
}
__device__ __forceinline__ ushort_t f2bf(float f) {
    unsigned v = __float_as_uint(f);
    v += 0x7FFFu + ((v >> 16) & 1u);   // round-to-nearest-even
    return (ushort_t)(v >> 16);
}

// direct global->LDS 16B copy (no VGPR round-trip). Dest must be
// wave-uniform base + lane*16 — our fragment staging layout is exactly that.
__device__ __forceinline__ void gload_lds16(const void* g, void* l) {
    __builtin_amdgcn_global_load_lds(
        (const __attribute__((address_space(1))) unsigned int*)g,
        (__attribute__((address_space(3))) unsigned int*)l,
        16, 0, 0);
}

__device__ __forceinline__ void split_f32x8(float4 f0, float4 f1, bf16x8& hi, bf16x8& lo) {
    float f[8] = {f0.x, f0.y, f0.z, f0.w, f1.x, f1.y, f1.z, f1.w};
#pragma unroll
    for (int i = 0; i < 8; ++i) {
        unsigned u = __float_as_uint(f[i]);
        hi[i] = (short)(u >> 16);
        float r = f[i] - __uint_as_float(u & 0xFFFF0000u);
        lo[i] = (short)f2bf(r);
    }
}

// W -> bf16 hi/lo fragment-major conversion body (one kt-block of one layer)
__device__ __forceinline__ void wconv_body(const float* __restrict__ W, int kt, int tid,
                                           ushort_t* __restrict__ wtf_hi,
                                           ushort_t* __restrict__ wtf_lo,
                                           ushort_t* smem) {
    ushort_t (*lds_hi)[256] = (ushort_t(*)[256])smem;
    ushort_t (*lds_lo)[256] = (ushort_t(*)[256])(smem + 8192);
    for (int c = 0; c < 32; ++c) {
        float f = W[(kt * 32 + c) * GCN_D + tid];
        unsigned u = __float_as_uint(f);
        lds_hi[c][tid] = (ushort_t)(u >> 16);              // truncation: exact residual
        float r = f - __uint_as_float(u & 0xFFFF0000u);
        lds_lo[c][tid] = f2bf(r);
    }
    __syncthreads();
#pragma unroll
    for (int q = 0; q < 4; ++q) {
        int slot = q * 256 + tid;          // 0..1023 = nt*64 + lane
        int lane = slot & 63, nt = slot >> 6;
        int n = nt * 16 + (lane & 15);
        int kl = (lane >> 4) * 8;
        ushort_t h8[8], l8[8];
#pragma unroll
        for (int j = 0; j < 8; ++j) { h8[j] = lds_hi[kl + j][n]; l8[j] = lds_lo[kl + j][n]; }
        size_t o = ((size_t)(kt * 16 + nt) * 64 + lane) * 8;
#pragma unroll
        for (int j = 0; j < 8; ++j) { wtf_hi[o + j] = h8[j]; wtf_lo[o + j] = l8[j]; }
    }
}

// layer-1 W conversion: must precede fused1 (whose gemm blocks read it).
__global__ __launch_bounds__(256) void wconv1_kernel(const float* __restrict__ W,
                                                     ushort_t* __restrict__ wtf) {
    __shared__ ushort_t smem[16384];
    wconv_body(W, blockIdx.x, threadIdx.x, wtf, wtf + 65536, smem);
}

// ================= fused: gemm_f32(layer1) | edge_mlp | wconvert(L2,L3) ==========
// NOTE R11 lesson: >64KB dynamic-LDS launches fail silently on this toolchain —
// all LDS here is static and <= 34KB.

__global__ __launch_bounds__(256) void fused1_kernel(
        const float* __restrict__ x, const ushort_t* __restrict__ wtf_hi1,
        const ushort_t* __restrict__ wtf_lo1, const float* __restrict__ b1,
        ushort_t* __restrict__ out_h,
        const float* __restrict__ attr, const int* __restrict__ dst,
        const float* __restrict__ mw1, const float* __restrict__ mb1,
        const float* __restrict__ mw2, const float* __restrict__ mb2,
        float* __restrict__ ew, u64* __restrict__ dc, int* __restrict__ rank,
        const float* __restrict__ W2, const float* __restrict__ W3,
        ushort_t* __restrict__ wtf) {
    __shared__ ushort_t smem[4 * 16 * 264];   // 33792B
    const int b = blockIdx.x;
    const int tid = threadIdx.x;

    if (b < GEMM_BLOCKS) {
        // ---- gemm_f32: 64 rows x 256 cols, split-precision, gload_lds-staged B ----
        const int lane = tid & 63;
        const int wv   = tid >> 6;
        const int r16  = lane & 15;
        const int kg   = lane >> 4;
        const int row0 = b * 64 + wv * 16;

        f32x4 acc[16];
#pragma unroll
        for (int nt = 0; nt < 16; ++nt) acc[nt] = (f32x4){0.f, 0.f, 0.f, 0.f};

        const int arow = row0 + r16;
        const float* ap = (arow < GCN_N) ? &x[(size_t)arow * GCN_D + kg * 8] : nullptr;
        bf16x8* sH = (bf16x8*)smem;
        bf16x8* sL = ((bf16x8*)smem) + 1024;

#pragma unroll 1
        for (int kt = 0; kt < 8; ++kt) {
            // issue direct global->LDS staging (16B/lane, 8 per thread)
            const bf16x8* gh = (const bf16x8*)wtf_hi1 + (size_t)kt * 1024;
            const bf16x8* gl = (const bf16x8*)wtf_lo1 + (size_t)kt * 1024;
#pragma unroll
            for (int c = 0; c < 4; ++c) {
                gload_lds16(gh + c * 256 + tid, sH + c * 256 + tid);
                gload_lds16(gl + c * 256 + tid, sL + c * 256 + tid);
            }
            // A load + split overlap the staging latency
            float4 f0 = make_float4(0.f, 0.f, 0.f, 0.f), f1 = f0;
            if (ap) {
                f0 = *(const float4*)(ap + kt * 32);
                f1 = *(const float4*)(ap + kt * 32 + 4);
            }
            bf16x8 a_hi, a_lo;
            split_f32x8(f0, f1, a_hi, a_lo);
            __syncthreads();   // drains vmcnt -> staging complete
#pragma unroll
            for (int nt = 0; nt < 16; ++nt) {
                bf16x8 bh = sH[nt * 64 + lane];
                bf16x8 bl = sL[nt * 64 + lane];
                acc[nt] = __builtin_amdgcn_mfma_f32_16x16x32_bf16(a_hi, bh, acc[nt], 0, 0, 0);
                acc[nt] = __builtin_amdgcn_mfma_f32_16x16x32_bf16(a_lo, bh, acc[nt], 0, 0, 0);
                acc[nt] = __builtin_amdgcn_mfma_f32_16x16x32_bf16(a_hi, bl, acc[nt], 0, 0, 0);
            }
            __syncthreads();
        }

        ushort_t* my = smem + wv * (16 * 264);
#pragma unroll
        for (int nt = 0; nt < 16; ++nt) {
            float bv = b1[nt * 16 + r16];
#pragma unroll
            for (int r = 0; r < 4; ++r)
                my[(kg * 4 + r) * 264 + nt * 16 + r16] = f2bf(acc[nt][r] + bv);
        }
#pragma unroll 4
        for (int r = 0; r < 16; ++r) {
            int row = row0 + r;
            if (row < GCN_N) {
                ushort4 v = *(ushort4*)&my[r * 264 + lane * 4];
                *(ushort4*)&out_h[(size_t)row * GCN_D + lane * 4] = v;
            }
        }
    } else if (b < GEMM_BLOCKS + EDGE_BLOCKS) {
        int e = (b - GEMM_BLOCKS) * 256 + tid;
        if (e >= GCN_E) return;
        float a = attr[e];
        float s = mb2[0];
#pragma unroll
        for (int j = 0; j < 8; ++j) {
            float hj = fmaf(a, mw1[j], mb1[j]);
            hj = fmaxf(hj, 0.0f);
            s = fmaf(hj, mw2[j], s);
        }
        float w = 1.0f / (1.0f + expf(-s));
        ew[e] = w;
        u64 pack = (1ull << 40) + (u64)((double)w * 4294967296.0);
        u64 old = atomicAdd(&dc[dst[e]], pack);
        rank[e] = (int)(old >> 40);
    } else {
        const int wb = b - GEMM_BLOCKS - EDGE_BLOCKS;   // 0..15
        const int layer = 1 + (wb >> 3);                // 1 or 2
        const int kt = wb & 7;
        const float* W = (layer == 1) ? W2 : W3;
        ushort_t* wtf_hi = wtf + (size_t)layer * 2 * 65536;
        wconv_body(W, kt, tid, wtf_hi, wtf_hi + 65536, smem);
    }
}

// ---------------- preprocessing (post-fused) ----------------

__global__ __launch_bounds__(1024) void scan1_kernel(const u64* __restrict__ dc,
                                                     int* __restrict__ part,
                                                     int* __restrict__ bsum,
                                                     float* __restrict__ dinv,
                                                     float* __restrict__ invdeg, int n) {
    __shared__ int s[1024];
    int tid = threadIdx.x;
    int i = blockIdx.x * 1024 + tid;
    u64 dv = (i < n) ? dc[i] : 0ull;
    int v = (int)(dv >> 40);
    s[tid] = v;
    if (i < n) {
        float wsum = (float)((double)(dv & ((1ull << 40) - 1)) * (1.0 / 4294967296.0));
        float d = 1.0f + wsum;
        dinv[i] = rsqrtf(d);
        invdeg[i] = 1.0f / d;
    }
    __syncthreads();
#pragma unroll
    for (int d = 1; d < 1024; d <<= 1) {
        int t = (tid >= d) ? s[tid - d] : 0;
        __syncthreads();
        s[tid] += t;
        __syncthreads();
    }
    if (i < n) part[i] = s[tid] - v;  // exclusive within block
    if (tid == 1023) bsum[blockIdx.x] = s[1023];
}

__global__ void scan2_kernel(int* bsum, int nb) {
    int t = threadIdx.x;
    int orig = (t < nb) ? bsum[t] : 0;
    int v = orig;
#pragma unroll
    for (int d = 1; d < 64; d <<= 1) {
        int u = __shfl_up(v, d, 64);
        if (t >= d) v += u;
    }
    if (t < nb) bsum[t] = v - orig;   // exclusive
}

__global__ void scan3_kernel(const int* __restrict__ part, const int* __restrict__ bsum,
                             int* __restrict__ offs, int n, int e_total) {
    int i = blockIdx.x * blockDim.x + threadIdx.x;
    if (i < n) offs[i] = part[i] + bsum[i >> 10];
    if (i == 0) offs[n] = e_total;
}

__global__ void scatter_kernel(const int* __restrict__ src, const int* __restrict__ dst,
                               const float* __restrict__ ew, const float* __restrict__ dinv,
                               const int* __restrict__ offs, const int* __restrict__ rank,
                               int2* __restrict__ csr, int e_count) {
    int e = blockIdx.x * blockDim.x + threadIdx.x;
    if (e >= e_count) return;
    int sN = src[e], dN = dst[e];
    int pos = offs[dN] + rank[e];
    float w = dinv[sN] * ew[e] * dinv[dN];
    csr[pos] = make_int2(sN, __float_as_int(w));
}

// ---------------- MFMA GEMM (layers 2,3): bf16 A, W_hi only, gload_lds-staged ---------
// Stages a kt-PAIR (32KB) per barrier pair via direct global->LDS.

__global__ __launch_bounds__(256) void mfma_gemm_bf16_kernel(
        const ushort_t* __restrict__ a_in,
        const ushort_t* __restrict__ wtf_hi,
        const float* __restrict__ bias,
        ushort_t* __restrict__ out_h,
        int n_rows) {
    __shared__ ushort_t smem[4 * 16 * 264];   // 33792B >= 32KB stage area
    const int tid  = threadIdx.x;
    const int lane = tid & 63;
    const int wv   = tid >> 6;
    const int r16  = lane & 15;
    const int kg   = lane >> 4;
    const int row0 = blockIdx.x * 64 + wv * 16;

    f32x4 acc[16];
#pragma unroll
    for (int nt = 0; nt < 16; ++nt) acc[nt] = (f32x4){0.f, 0.f, 0.f, 0.f};

    const int arow = row0 + r16;
    const ushort_t* ap = (arow < n_rows) ? &a_in[(size_t)arow * GCN_D + kg * 8] : nullptr;
    bf16x8* sH = (bf16x8*)smem;               // 2048 fragments (32KB)

#pragma unroll 1
    for (int kp = 0; kp < 4; ++kp) {          // kt pair
        const bf16x8* gh = (const bf16x8*)wtf_hi + (size_t)kp * 2048;
#pragma unroll
        for (int j = 0; j < 8; ++j)
            gload_lds16(gh + j * 256 + tid, sH + j * 256 + tid);
        bf16x8 a0 = (bf16x8){0,0,0,0,0,0,0,0}, a1 = a0;
        if (ap) {
            a0 = *(const bf16x8*)(ap + (kp * 2) * 32);
            a1 = *(const bf16x8*)(ap + (kp * 2 + 1) * 32);
        }
        __syncthreads();   // drains vmcnt -> staging complete
#pragma unroll
        for (int nt = 0; nt < 16; ++nt) {
            bf16x8 bh0 = sH[nt * 64 + lane];
            bf16x8 bh1 = sH[1024 + nt * 64 + lane];
            acc[nt] = __builtin_amdgcn_mfma_f32_16x16x32_bf16(a0, bh0, acc[nt], 0, 0, 0);
            acc[nt] = __builtin_amdgcn_mfma_f32_16x16x32_bf16(a1, bh1, acc[nt], 0, 0, 0);
        }
        __syncthreads();
    }

    ushort_t* my = smem + wv * (16 * 264);
#pragma unroll
    for (int nt = 0; nt < 16; ++nt) {
        float bv = bias[nt * 16 + r16];
#pragma unroll
        for (int r = 0; r < 4; ++r)
            my[(kg * 4 + r) * 264 + nt * 16 + r16] = f2bf(acc[nt][r] + bv);
    }
#pragma unroll 4
    for (int r = 0; r < 16; ++r) {
        int row = row0 + r;
        if (row < n_rows) {
            ushort4 v = *(ushort4*)&my[r * 264 + lane * 4];
            *(ushort4*)&out_h[(size_t)row * GCN_D + lane * 4] = v;
        }
    }
}

// ---------------- SpMM: agg = A_norm*h + diag(1/deg)*h ----------------

template <int OUT_BF16>
__global__ __launch_bounds__(256) void spmm_kernel(const ushort_t* __restrict__ h,
                                                   const int* __restrict__ offs,
                                                   const int2* __restrict__ csr,
                                                   const float* __restrict__ invdeg,
                                                   void* __restrict__ outp, int n) {
    int wid = (blockIdx.x * blockDim.x + threadIdx.x) >> 6;
    int lane = threadIdx.x & 63;
    if (wid >= n) return;
    const ushort4* h4 = (const ushort4*)h;
    ushort4 sv = h4[(size_t)wid * 64 + lane];
    float sw = invdeg[wid];
    float4 acc;
    acc.x = bf2f(sv.x) * sw; acc.y = bf2f(sv.y) * sw;
    acc.z = bf2f(sv.z) * sw; acc.w = bf2f(sv.w) * sw;
    int e0 = offs[wid], e1 = offs[wid + 1];
    int k = e0;
    for (; k + 8 <= e1; k += 8) {
        int2 ee[8]; ushort4 vv[8];
#pragma unroll
        for (int u = 0; u < 8; ++u) ee[u] = csr[k + u];
#pragma unroll
        for (int u = 0; u < 8; ++u) vv[u] = h4[(size_t)ee[u].x * 64 + lane];
#pragma unroll
        for (int u = 0; u < 8; ++u) {
            float w = __int_as_float(ee[u].y);
            acc.x = fmaf(w, bf2f(vv[u].x), acc.x);
            acc.y = fmaf(w, bf2f(vv[u].y), acc.y);
            acc.z = fmaf(w, bf2f(vv[u].z), acc.z);
            acc.w = fmaf(w, bf2f(vv[u].w), acc.w);
        }
    }
    for (; k < e1; ++k) {
        int2 e = csr[k];
        float w = __int_as_float(e.y);
        ushort4 hv = h4[(size_t)e.x * 64 + lane];
        acc.x = fmaf(w, bf2f(hv.x), acc.x);
        acc.y = fmaf(w, bf2f(hv.y), acc.y);
        acc.z = fmaf(w, bf2f(hv.z), acc.z);
        acc.w = fmaf(w, bf2f(hv.w), acc.w);
    }
    if (OUT_BF16) {
        ushort4 o;
        o.x = f2bf(fmaxf(acc.x, 0.f));
        o.y = f2bf(fmaxf(acc.y, 0.f));
        o.z = f2bf(fmaxf(acc.z, 0.f));
        o.w = f2bf(fmaxf(acc.w, 0.f));
        ((ushort4*)outp)[(size_t)wid * 64 + lane] = o;
    } else {
        ((float4*)outp)[(size_t)wid * 64 + lane] = acc;
    }
}

// ---------------- launch ----------------

extern "C" void kernel_launch(void* const* d_in, const int* in_sizes, int n_in,
                              void* d_out, int out_size, void* d_ws, size_t ws_size,
                              hipStream_t stream) {
    const float* x    = (const float*)d_in[0];
    const int*   ei   = (const int*)d_in[1];
    const float* attr = (const float*)d_in[2];
    const float* W1 = (const float*)d_in[3];  const float* b1 = (const float*)d_in[4];
    const float* W2 = (const float*)d_in[5];  const float* b2 = (const float*)d_in[6];
    const float* W3 = (const float*)d_in[7];  const float* b3 = (const float*)d_in[8];
    const float* mw1 = (const float*)d_in[9]; const float* mb1 = (const float*)d_in[10];
    const float* mw2 = (const float*)d_in[11];const float* mb2 = (const float*)d_in[12];
    float* out = (float*)d_out;

    const int N = GCN_N, E = GCN_E;
    const int* srcI = ei;
    const int* dstI = ei + E;

    char* ws = (char*)d_ws;
    float* ew     = (float*)ws;                      ws += (size_t)E * 4;
    int*   rank   = (int*)ws;                        ws += (size_t)E * 4;
    u64*   dc     = (u64*)(((uintptr_t)ws + 255) & ~(uintptr_t)255); ws = (char*)(dc + N);
    float* dinv   = (float*)ws;                      ws += (size_t)N * 4;
    float* invdeg = (float*)ws;                      ws += (size_t)N * 4;
    int*   offs   = (int*)ws;                        ws += (size_t)(N + 1) * 4;
    int*   bsum   = (int*)ws;                        ws += 64 * 4;
    int*   part   = (int*)ws;                        ws += (size_t)N * 4;
    int2*  csr    = (int2*)(((uintptr_t)ws + 255) & ~(uintptr_t)255); ws = (char*)(csr + E);
    ushort_t* h   = (ushort_t*)(((uintptr_t)ws + 255) & ~(uintptr_t)255);  // N*256 bf16
    ws = (char*)(h + (size_t)N * GCN_D);
    ushort_t* act = (ushort_t*)(((uintptr_t)ws + 255) & ~(uintptr_t)255);  // N*256 bf16
    ws = (char*)(act + (size_t)N * GCN_D);
    ushort_t* wtf = (ushort_t*)(((uintptr_t)ws + 255) & ~(uintptr_t)255);  // [3][2][65536]
    ushort_t* wtf_hi1 = wtf;
    ushort_t* wtf_lo1 = wtf + 65536;
    ushort_t* wtf_hi2 = wtf + 2 * 65536;
    ushort_t* wtf_hi3 = wtf + 4 * 65536;

    hipMemsetAsync(dc, 0, (size_t)N * sizeof(u64), stream);
    wconv1_kernel<<<8, 256, 0, stream>>>(W1, wtf);
    fused1_kernel<<<GEMM_BLOCKS + EDGE_BLOCKS + 16, 256, 0, stream>>>(
        x, wtf_hi1, wtf_lo1, b1, h,
        attr, dstI, mw1, mb1, mw2, mb2, ew, dc, rank,
        W2, W3, wtf);
    int nb = (N + 1023) / 1024;
    scan1_kernel<<<nb, 1024, 0, stream>>>(dc, part, bsum, dinv, invdeg, N);
    scan2_kernel<<<1, 64, 0, stream>>>(bsum, nb);
    scan3_kernel<<<(N + 255) / 256, 256, 0, stream>>>(part, bsum, offs, N, E);
    scatter_kernel<<<(E + 255) / 256, 256, 0, stream>>>(srcI, dstI, ew, dinv, offs, rank,
                                                        csr, E);

    const int gemm_grid = (N + 63) / 64;
    const int spmm_grid = (N * 64 + 255) / 256;

    // layer 1 spmm (h computed inside fused1)
    spmm_kernel<1><<<spmm_grid, 256, 0, stream>>>(h, offs, csr, invdeg, act, N);
    // layer 2
    mfma_gemm_bf16_kernel<<<gemm_grid, 256, 0, stream>>>(act, wtf_hi2, b2, h, N);
    spmm_kernel<1><<<spmm_grid, 256, 0, stream>>>(h, offs, csr, invdeg, act, N);
    // layer 3
    mfma_gemm_bf16_kernel<<<gemm_grid, 256, 0, stream>>>(act, wtf_hi3, b3, h, N);
    spmm_kernel<0><<<spmm_grid, 256, 0, stream>>>(h, offs, csr, invdeg, out, N);
}